// Round 1
// baseline (947.000 us; speedup 1.0000x reference)
//
#include <hip/hip_runtime.h>

typedef float  f32x4 __attribute__((ext_vector_type(4)));
typedef short  s16x8 __attribute__((ext_vector_type(8)));

#define EPS_LN2      0.0017328679513998632f   /* eps*ln2, eps = 0.0025 */
#define INV_EPS_LN2  577.0780163555852f       /* 1/(eps*ln2) */
#define LOG2_36      5.169925001442312f

__device__ __forceinline__ float bf2f(short h) {
  unsigned int u = ((unsigned int)(unsigned short)h) << 16;
  float f; __builtin_memcpy(&f, &u, 4); return f;
}
__device__ __forceinline__ short f2bf(float x) {
  unsigned int u; __builtin_memcpy(&u, &x, 4);
  u = (u + 0x7FFFu + ((u >> 16) & 1u)) >> 16;   // RNE
  return (short)u;
}

// ---------------------------------------------------------------------------
// Pack W_rt [768,50] and W_ri [2048,50] into MFMA B-fragment order (bf16),
// N padded 50->64 with zeros. Frag f = (k32*4 + ct)*64 + lane, 8 bf16 each.
// ---------------------------------------------------------------------------
__global__ __launch_bounds__(256) void k_pack(const float* __restrict__ W_rt,
                                              const float* __restrict__ W_ri,
                                              short* __restrict__ frt,
                                              short* __restrict__ fri) {
  int slot = blockIdx.x * 256 + threadIdx.x;   // 22528 total
  const float* W; short* dst; int f;
  if (slot < 6144) { W = W_rt; dst = frt; f = slot; }
  else             { W = W_ri; dst = fri; f = slot - 6144; }
  int k32 = f >> 8, rem = f & 255, ct = rem >> 6, l = rem & 63;
  int col = ct * 16 + (l & 15);
  int k0  = k32 * 32 + (l >> 4) * 8;
  s16x8 p;
#pragma unroll
  for (int c = 0; c < 8; ++c) {
    float v = (col < 50) ? W[(k0 + c) * 50 + col] : 0.f;
    p[c] = f2bf(v);
  }
  *(s16x8*)(dst + (long)f * 8) = p;
}

// ---------------------------------------------------------------------------
// Projection GEMM: out[M][64] = relu(A[M][K] @ W + bias), bf16 MFMA,
// one wave per 16-row tile, 4 col-tiles (N=64). cols >=50 written as 0.
// ---------------------------------------------------------------------------
template<int K32>
__global__ __launch_bounds__(256) void k_proj(const float* __restrict__ A,
                                              const short* __restrict__ Bf,
                                              const float* __restrict__ bias,
                                              float* __restrict__ out) {
  int wave = threadIdx.x >> 6, lane = threadIdx.x & 63;
  int tile = blockIdx.x * 4 + wave;
  int row0 = tile * 16;
  int rl = lane & 15, q = lane >> 4;
  const int K = K32 * 32;
  const float* ar = A + (long)(row0 + rl) * K + q * 8;
  f32x4 acc[4];
#pragma unroll
  for (int ct = 0; ct < 4; ++ct) acc[ct] = (f32x4){0.f, 0.f, 0.f, 0.f};
  for (int k32 = 0; k32 < K32; ++k32) {
    f32x4 a0 = *(const f32x4*)(ar + k32 * 32);
    f32x4 a1 = *(const f32x4*)(ar + k32 * 32 + 4);
    s16x8 af;
    af[0]=f2bf(a0[0]); af[1]=f2bf(a0[1]); af[2]=f2bf(a0[2]); af[3]=f2bf(a0[3]);
    af[4]=f2bf(a1[0]); af[5]=f2bf(a1[1]); af[6]=f2bf(a1[2]); af[7]=f2bf(a1[3]);
    const short* bp = Bf + (long)(k32 * 4) * 512 + lane * 8;
#pragma unroll
    for (int ct = 0; ct < 4; ++ct) {
      s16x8 bfr = *(const s16x8*)(bp + ct * 512);
      acc[ct] = __builtin_amdgcn_mfma_f32_16x16x32_bf16(af, bfr, acc[ct], 0, 0, 0);
    }
  }
#pragma unroll
  for (int ct = 0; ct < 4; ++ct) {
    int col = ct * 16 + rl;
    float bv = (col < 50) ? bias[col] : 0.f;
#pragma unroll
    for (int r = 0; r < 4; ++r) {
      int grow = row0 + q * 4 + r;               // D row = quad*4+reg (m89)
      float o = fmaxf(acc[ct][r] + bv, 0.f);
      out[(long)grow * 64 + col] = (col < 50) ? o : 0.f;
    }
  }
}

// ---------------------------------------------------------------------------
// Global MLP head -> mix_pred[128][2]. One block per 4 batch rows.
// ---------------------------------------------------------------------------
__global__ __launch_bounds__(256) void k_mlp(
    const float* __restrict__ txt_global, const float* __restrict__ img_global,
    const float* __restrict__ social,
    const float* __restrict__ W_stat, const float* __restrict__ b_stat,
    const float* __restrict__ W_gt, const float* __restrict__ b_gt,
    const float* __restrict__ W_gi, const float* __restrict__ b_gi,
    const float* __restrict__ W_m1, const float* __restrict__ b_m1,
    const float* __restrict__ W_m2, const float* __restrict__ b_m2,
    float* __restrict__ mix) {
  __shared__ float sx[4][768];
  __shared__ float sgi[4][2048];
  __shared__ float ssoc_in[4][10];
  __shared__ float ssoc[4][100];
  __shared__ float sm[4][200];
  __shared__ float sh[4][100];
  int t = threadIdx.x, r0 = blockIdx.x * 4;
  for (int r = 0; r < 4; ++r) {
    for (int c = t; c < 768;  c += 256) sx[r][c]  = txt_global[(r0 + r) * 768 + c];
    for (int c = t; c < 2048; c += 256) sgi[r][c] = img_global[(r0 + r) * 2048 + c];
    if (t < 10) ssoc_in[r][t] = social[(r0 + r) * 10 + t];
  }
  __syncthreads();
  if (t < 100) {
    for (int r = 0; r < 4; ++r) {
      float a = b_stat[t];
      for (int k = 0; k < 10; ++k) a += ssoc_in[r][k] * W_stat[k * 100 + t];
      ssoc[r][t] = fmaxf(a, 0.f);
    }
  }
  __syncthreads();
  if (t < 200) {
    float at[4], ai[4];
#pragma unroll
    for (int r = 0; r < 4; ++r) { at[r] = b_gt[t]; ai[r] = b_gi[t]; }
#pragma unroll 4
    for (int k = 0; k < 768; ++k) {
      float w = W_gt[k * 200 + t];
#pragma unroll
      for (int r = 0; r < 4; ++r) at[r] += sx[r][k] * w;
    }
#pragma unroll 4
    for (int k = 0; k < 100; ++k) {
      float w = W_gt[(768 + k) * 200 + t];
#pragma unroll
      for (int r = 0; r < 4; ++r) at[r] += ssoc[r][k] * w;
    }
#pragma unroll 4
    for (int k = 0; k < 2048; ++k) {
      float w = W_gi[k * 200 + t];
#pragma unroll
      for (int r = 0; r < 4; ++r) ai[r] += sgi[r][k] * w;
    }
#pragma unroll
    for (int r = 0; r < 4; ++r) sm[r][t] = fmaxf(at[r], 0.f) + fmaxf(ai[r], 0.f);
  }
  __syncthreads();
  if (t < 100) {
    for (int r = 0; r < 4; ++r) {
      float a = b_m1[t];
#pragma unroll 4
      for (int k = 0; k < 200; ++k) a += sm[r][k] * W_m1[k * 100 + t];
      sh[r][t] = fmaxf(a, 0.f);
    }
  }
  __syncthreads();
  if (t < 8) {
    int r = t >> 1, c = t & 1;
    float a = b_m2[c];
    for (int k = 0; k < 100; ++k) a += sh[r][k] * W_m2[k * 2 + c];
    mix[(r0 + r) * 2 + c] = a;
  }
}

// ---------------------------------------------------------------------------
// Merged Sinkhorn kernel. role 0: xx (n x n), role 1: xy (n x 36),
// role 2: yy (36 x 36). Log-domain, exp2 units, D = -C/(eps*ln2).
// ---------------------------------------------------------------------------
#define SK_SMEM 50736

__global__ __launch_bounds__(1024) void k_sink(
    const float* __restrict__ tr, const float* __restrict__ ir,
    const int* __restrict__ amask, float* __restrict__ Cxx,
    float* __restrict__ Sxy, float* __restrict__ Sxx, float* __restrict__ Syy) {
  __shared__ __align__(16) char smem[SK_SMEM];
  int role = blockIdx.x >> 7;
  int b    = blockIdx.x & 127;
  int tid  = threadIdx.x;

  if (role == 0) {
    // ====================== XX ======================
    short* Xf    = (short*)smem;                 // [16 tiles][2 k32][64 lanes][8] = 32 KB
    float* norms = (float*)(smem + 32768);       // [256]
    float* sA    = (float*)(smem + 33792);       // padded alpha [272]
    float* sF    = (float*)(smem + 34880);       // [256]
    float* sG    = (float*)(smem + 35904);       // [256]
    int*   nsh   = (int*)  (smem + 36928);
    if (tid < 64) {
      int c = 0;
      for (int i = tid; i < 256; i += 64) c += amask[b * 256 + i];
#pragma unroll
      for (int o = 1; o < 64; o <<= 1) c += __shfl_xor(c, o);
      if (tid == 0) *nsh = c;
    }
    const float* Xg = tr + (long)b * 256 * 64;
    for (int slot = tid; slot < 2048; slot += 1024) {
      int t = slot >> 7, k32 = (slot >> 6) & 1, l = slot & 63;
      int row = t * 16 + (l & 15), k0 = k32 * 32 + (l >> 4) * 8;
      const float* src = Xg + row * 64 + k0;
      f32x4 a0 = *(const f32x4*)src, a1 = *(const f32x4*)(src + 4);
      s16x8 p;
      p[0]=f2bf(a0[0]); p[1]=f2bf(a0[1]); p[2]=f2bf(a0[2]); p[3]=f2bf(a0[3]);
      p[4]=f2bf(a1[0]); p[5]=f2bf(a1[1]); p[6]=f2bf(a1[2]); p[7]=f2bf(a1[3]);
      *(s16x8*)(Xf + slot * 8) = p;
    }
    __syncthreads();
    int n = *nsh;
    // G = X X^T via MFMA. wave wv owns 16-row strip.
    int wv = tid >> 6, lane = tid & 63, q = lane >> 4;
    f32x4 acc[16];
#pragma unroll
    for (int ct = 0; ct < 16; ++ct) acc[ct] = (f32x4){0.f, 0.f, 0.f, 0.f};
    s16x8 afr0 = *(const s16x8*)(Xf + ((wv * 2 + 0) * 64 + lane) * 8);
    s16x8 afr1 = *(const s16x8*)(Xf + ((wv * 2 + 1) * 64 + lane) * 8);
#pragma unroll
    for (int ct = 0; ct < 16; ++ct) {
      s16x8 b0 = *(const s16x8*)(Xf + ((ct * 2 + 0) * 64 + lane) * 8);
      s16x8 b1 = *(const s16x8*)(Xf + ((ct * 2 + 1) * 64 + lane) * 8);
      acc[ct] = __builtin_amdgcn_mfma_f32_16x16x32_bf16(afr0, b0, acc[ct], 0, 0, 0);
      acc[ct] = __builtin_amdgcn_mfma_f32_16x16x32_bf16(afr1, b1, acc[ct], 0, 0, 0);
    }
#pragma unroll
    for (int r = 0; r < 4; ++r) {                 // diag of tile (wv,wv) = ||x||^2
      int m_ = q * 4 + r;
      if ((lane & 15) == m_) norms[wv * 16 + m_] = acc[wv][r];
    }
    __syncthreads();
    float* Cwb = Cxx + (long)b * 65536;           // D = -C/(eps ln2), f32, global
#pragma unroll
    for (int ct = 0; ct < 16; ++ct) {
      int gj = ct * 16 + (lane & 15);
      float nj = norms[gj];
#pragma unroll
      for (int r = 0; r < 4; ++r) {
        int gi = wv * 16 + q * 4 + r;
        Cwb[gi * 256 + gj] = (acc[ct][r] - 0.5f * (norms[gi] + nj)) * INV_EPS_LN2;
      }
    }
    __syncthreads();
    int j = tid >> 2, kk = tid & 3, i0 = kk * 64;
    float Creg[64];
#pragma unroll
    for (int t = 0; t < 64; ++t) Creg[t] = Cwb[(i0 + t) * 256 + j];
    float log2n = log2f((float)n);
    if (tid < 256) { sF[tid] = 0.f; sA[tid + (tid >> 6)] = -log2n; }
    __syncthreads();
    const float* ap = sA + i0 + kk;               // padded base, conflict-free
    int iend = n - i0; if (iend > 64) iend = 64;
    for (int h = 0; h < 40; ++h) {
      float m = -1e30f;
#pragma unroll
      for (int t = 0; t < 64; ++t)
        if (t < iend) m = fmaxf(m, ap[t] + Creg[t]);
      m = fmaxf(m, __shfl_xor(m, 1));
      m = fmaxf(m, __shfl_xor(m, 2));
      float s = 0.f;
#pragma unroll
      for (int t = 0; t < 64; ++t)
        if (t < iend) s += exp2f(ap[t] + Creg[t] - m);
      s += __shfl_xor(s, 1);
      s += __shfl_xor(s, 2);
      __syncthreads();
      if (kk == 0 && j < n) {
        float lse = log2f(s) + m;
        ((h & 1) ? sF : sG)[j] = -EPS_LN2 * lse;
        sA[j + (j >> 6)] = -log2n - lse;
      }
      __syncthreads();
    }
    if (tid < 64) {
      float a = 0.f;
      for (int i = tid; i < n; i += 64) a += sF[i] + sG[i];
#pragma unroll
      for (int o = 1; o < 64; o <<= 1) a += __shfl_xor(a, o);
      if (tid == 0) Sxx[b] = a / n;
    }
  } else if (role == 1) {
    // ====================== XY ======================
    float* Ys  = (float*)smem;                    // [36][64]
    float* Cs  = (float*)(smem + 9216);           // [256][37]
    float* nx  = (float*)(smem + 47104);          // [256]
    float* ny  = (float*)(smem + 48128);          // [36]
    float* sA  = (float*)(smem + 48288);          // padded alpha [272]
    float* sB  = (float*)(smem + 49376);          // beta [36]
    float* sF  = (float*)(smem + 49536);          // [256]
    float* sG  = (float*)(smem + 50560);          // [36]
    int*   nsh = (int*)  (smem + 50720);
    if (tid < 64) {
      int c = 0;
      for (int i = tid; i < 256; i += 64) c += amask[b * 256 + i];
#pragma unroll
      for (int o = 1; o < 64; o <<= 1) c += __shfl_xor(c, o);
      if (tid == 0) *nsh = c;
    }
    const float* Xg = tr + (long)b * 256 * 64;
    const float* Yg = ir + (long)b * 36 * 64;
    for (int idx = tid; idx < 576; idx += 1024) {
      int row = idx >> 4, q4 = idx & 15;
      *(f32x4*)(Ys + row * 64 + q4 * 4) = *(const f32x4*)(Yg + row * 64 + q4 * 4);
    }
    __syncthreads();
    int n = *nsh;
    if (tid < 256) {
      float a = 0.f;
#pragma unroll
      for (int q4 = 0; q4 < 13; ++q4) {
        f32x4 v = *(const f32x4*)(Xg + tid * 64 + q4 * 4);
        a += v[0]*v[0] + v[1]*v[1] + v[2]*v[2] + v[3]*v[3];
      }
      nx[tid] = a;
    } else if (tid < 292) {
      int jj = tid - 256; float a = 0.f;
#pragma unroll
      for (int q4 = 0; q4 < 13; ++q4) {
        f32x4 v = *(const f32x4*)(Ys + jj * 64 + q4 * 4);
        a += v[0]*v[0] + v[1]*v[1] + v[2]*v[2] + v[3]*v[3];
      }
      ny[jj] = a;
    }
    __syncthreads();
    if (tid < 1008) {
      int ii = tid / 36, jj = tid - ii * 36;
      f32x4 yr[13];
#pragma unroll
      for (int q4 = 0; q4 < 13; ++q4) yr[q4] = *(const f32x4*)(Ys + jj * 64 + q4 * 4);
      float nyj = ny[jj];
      for (int i = ii; i < 256; i += 28) {
        float d = 0.f;
#pragma unroll
        for (int q4 = 0; q4 < 13; ++q4) {
          f32x4 xv = *(const f32x4*)(Xg + i * 64 + q4 * 4);
          d += xv[0]*yr[q4][0] + xv[1]*yr[q4][1] + xv[2]*yr[q4][2] + xv[3]*yr[q4][3];
        }
        Cs[i * 37 + jj] = (d - 0.5f * (nx[i] + nyj)) * INV_EPS_LN2;
      }
    }
    __syncthreads();
    int jg = tid >> 4, kg = tid & 15;             // g-role: column jg, slice kg
    float Cg[16];
    if (jg < 36) {
#pragma unroll
      for (int t = 0; t < 16; ++t) Cg[t] = Cs[(kg * 16 + t) * 37 + jg];
    }
    int fi = tid >> 2, kf = tid & 3;              // f-role: row fi, slice kf
    float Cf[9];
#pragma unroll
    for (int t = 0; t < 9; ++t) {
      int jj2 = kf * 9 + t;
      Cf[t] = (jj2 < 36) ? Cs[fi * 37 + jj2] : 0.f;
    }
    float log2n = log2f((float)n);
    if (tid < 256) { sF[tid] = 0.f; sA[tid + (tid >> 4)] = -log2n; }
    __syncthreads();
    const float* agp = sA + kg * 17;
    int gend = n - kg * 16; if (gend > 16) gend = 16;
    for (int it = 0; it < 20; ++it) {
      float gm = -1e30f, gs = 0.f;
      if (jg < 36) {
#pragma unroll
        for (int t = 0; t < 16; ++t)
          if (t < gend) gm = fmaxf(gm, agp[t] + Cg[t]);
        gm = fmaxf(gm, __shfl_xor(gm, 1)); gm = fmaxf(gm, __shfl_xor(gm, 2));
        gm = fmaxf(gm, __shfl_xor(gm, 4)); gm = fmaxf(gm, __shfl_xor(gm, 8));
#pragma unroll
        for (int t = 0; t < 16; ++t)
          if (t < gend) gs += exp2f(agp[t] + Cg[t] - gm);
        gs += __shfl_xor(gs, 1); gs += __shfl_xor(gs, 2);
        gs += __shfl_xor(gs, 4); gs += __shfl_xor(gs, 8);
      }
      __syncthreads();
      if (jg < 36 && kg == 0) {
        float lse = log2f(gs) + gm;
        sG[jg] = -EPS_LN2 * lse;
        sB[jg] = -LOG2_36 - lse;
      }
      __syncthreads();
      float fm = -1e30f, fs = 0.f;
#pragma unroll
      for (int t = 0; t < 9; ++t) {
        int jj2 = kf * 9 + t;
        if (jj2 < 36) fm = fmaxf(fm, sB[jj2] + Cf[t]);
      }
      fm = fmaxf(fm, __shfl_xor(fm, 1)); fm = fmaxf(fm, __shfl_xor(fm, 2));
#pragma unroll
      for (int t = 0; t < 9; ++t) {
        int jj2 = kf * 9 + t;
        if (jj2 < 36) fs += exp2f(sB[jj2] + Cf[t] - fm);
      }
      fs += __shfl_xor(fs, 1); fs += __shfl_xor(fs, 2);
      __syncthreads();
      if (kf == 0 && fi < n) {
        float lse = log2f(fs) + fm;
        sF[fi] = -EPS_LN2 * lse;
        sA[fi + (fi >> 4)] = -log2n - lse;
      }
      __syncthreads();
    }
    if (tid < 64) {
      float a = 0.f;
      for (int i = tid; i < n; i += 64) a += sF[i];
      float g = (tid < 36) ? sG[tid] : 0.f;
#pragma unroll
      for (int o = 1; o < 64; o <<= 1) { a += __shfl_xor(a, o); g += __shfl_xor(g, o); }
      if (tid == 0) Sxy[b] = a / n + g / 36.f;
    }
  } else {
    // ====================== YY ======================
    float* Ys = (float*)smem;                     // [36][64]
    float* Cs = (float*)(smem + 9216);            // [36][37]
    float* ny = (float*)(smem + 48128);
    float* sA = (float*)(smem + 48288);           // [36]
    float* sF = (float*)(smem + 49536);
    float* sG = (float*)(smem + 50560);
    const float* Yg = ir + (long)b * 36 * 64;
    for (int idx = tid; idx < 576; idx += 1024) {
      int row = idx >> 4, q4 = idx & 15;
      *(f32x4*)(Ys + row * 64 + q4 * 4) = *(const f32x4*)(Yg + row * 64 + q4 * 4);
    }
    __syncthreads();
    if (tid < 36) {
      float a = 0.f;
#pragma unroll
      for (int q4 = 0; q4 < 13; ++q4) {
        f32x4 v = *(const f32x4*)(Ys + tid * 64 + q4 * 4);
        a += v[0]*v[0] + v[1]*v[1] + v[2]*v[2] + v[3]*v[3];
      }
      ny[tid] = a;
    }
    __syncthreads();
    if (tid < 1008) {
      int ii = tid / 36, jj = tid - ii * 36;
      f32x4 yr[13];
#pragma unroll
      for (int q4 = 0; q4 < 13; ++q4) yr[q4] = *(const f32x4*)(Ys + jj * 64 + q4 * 4);
      float nyj = ny[jj];
      for (int i = ii; i < 36; i += 28) {
        float d = 0.f;
#pragma unroll
        for (int q4 = 0; q4 < 13; ++q4) {
          f32x4 xv = *(const f32x4*)(Ys + i * 64 + q4 * 4);
          d += xv[0]*yr[q4][0] + xv[1]*yr[q4][1] + xv[2]*yr[q4][2] + xv[3]*yr[q4][3];
        }
        Cs[i * 37 + jj] = (d - 0.5f * (ny[i] + nyj)) * INV_EPS_LN2;
      }
    }
    __syncthreads();
    int j = tid >> 2, kk = tid & 3;
    float Creg[9];
    if (j < 36) {
#pragma unroll
      for (int t = 0; t < 9; ++t) {
        int i2 = kk * 9 + t;
        Creg[t] = (i2 < 36) ? Cs[i2 * 37 + j] : 0.f;
      }
    }
    if (tid < 36) { sF[tid] = 0.f; sA[tid] = -LOG2_36; }
    __syncthreads();
    for (int h = 0; h < 40; ++h) {
      float m = -1e30f, s = 0.f;
      if (j < 36) {
#pragma unroll
        for (int t = 0; t < 9; ++t) {
          int i2 = kk * 9 + t;
          if (i2 < 36) m = fmaxf(m, sA[i2] + Creg[t]);
        }
        m = fmaxf(m, __shfl_xor(m, 1)); m = fmaxf(m, __shfl_xor(m, 2));
#pragma unroll
        for (int t = 0; t < 9; ++t) {
          int i2 = kk * 9 + t;
          if (i2 < 36) s += exp2f(sA[i2] + Creg[t] - m);
        }
        s += __shfl_xor(s, 1); s += __shfl_xor(s, 2);
      }
      __syncthreads();
      if (j < 36 && kk == 0) {
        float lse = log2f(s) + m;
        ((h & 1) ? sF : sG)[j] = -EPS_LN2 * lse;
        sA[j] = -LOG2_36 - lse;
      }
      __syncthreads();
    }
    if (tid < 64) {
      float a = (tid < 36) ? sF[tid] + sG[tid] : 0.f;
#pragma unroll
      for (int o = 1; o < 64; o <<= 1) a += __shfl_xor(a, o);
      if (tid == 0) Syy[b] = a / 36.f;
    }
  }
}

// ---------------------------------------------------------------------------
// Final combine: w_dis -> w_pred, max with mix_pred, 2-way softmax.
// ---------------------------------------------------------------------------
__global__ void k_final(const float* __restrict__ mix, const float* __restrict__ sxy,
                        const float* __restrict__ sxx, const float* __restrict__ syy,
                        float* __restrict__ out) {
  int b = blockIdx.x * 64 + threadIdx.x;
  if (b < 128) {
    float w  = sxy[b] - 0.5f * (sxx[b] + syy[b]);
    float x0 = fmaxf(mix[b * 2 + 0], 1.0f - 0.01f * w);
    float x1 = fmaxf(mix[b * 2 + 1], 0.01f * w);
    float mx = fmaxf(x0, x1);
    float e0 = expf(x0 - mx), e1 = expf(x1 - mx);
    float inv = 1.f / (e0 + e1);
    out[b * 2 + 0] = e0 * inv;
    out[b * 2 + 1] = e1 * inv;
  }
}

// ---------------------------------------------------------------------------
extern "C" void kernel_launch(void* const* d_in, const int* in_sizes, int n_in,
                              void* d_out, int out_size, void* d_ws, size_t ws_size,
                              hipStream_t stream) {
  const float* txt_global = (const float*)d_in[0];
  const float* txt_region = (const float*)d_in[1];
  const float* img_global = (const float*)d_in[2];
  const float* img_region = (const float*)d_in[3];
  const float* social     = (const float*)d_in[4];
  const int*   attn_mask  = (const int*)  d_in[5];
  const float* W_stat = (const float*)d_in[6];  const float* b_stat = (const float*)d_in[7];
  const float* W_gt   = (const float*)d_in[8];  const float* b_gt   = (const float*)d_in[9];
  const float* W_gi   = (const float*)d_in[10]; const float* b_gi   = (const float*)d_in[11];
  const float* W_rt   = (const float*)d_in[12]; const float* b_rt   = (const float*)d_in[13];
  const float* W_ri   = (const float*)d_in[14]; const float* b_ri   = (const float*)d_in[15];
  const float* W_m1   = (const float*)d_in[16]; const float* b_m1   = (const float*)d_in[17];
  const float* W_m2   = (const float*)d_in[18]; const float* b_m2   = (const float*)d_in[19];

  float* ws = (float*)d_ws;
  float* ws_mix = ws;                 // 256
  float* ws_sxy = ws + 256;           // 128
  float* ws_sxx = ws + 384;           // 128
  float* ws_syy = ws + 512;           // 128
  short* ws_frt = (short*)(ws + 1024);   // 49152 shorts
  short* ws_fri = (short*)(ws + 25600);  // 131072 shorts
  float* ws_tr  = ws + 131072;        // [32768][64]
  float* ws_ir  = ws + 2228224;       // [4608][64]
  float* ws_cxx = ws + 2523136;       // [128][256][256]

  k_pack<<<88, 256, 0, stream>>>(W_rt, W_ri, ws_frt, ws_fri);
  k_mlp<<<32, 256, 0, stream>>>(txt_global, img_global, social,
                                W_stat, b_stat, W_gt, b_gt, W_gi, b_gi,
                                W_m1, b_m1, W_m2, b_m2, ws_mix);
  k_proj<24><<<512, 256, 0, stream>>>(txt_region, ws_frt, b_rt, ws_tr);
  k_proj<64><<<72, 256, 0, stream>>>(img_region, ws_fri, b_ri, ws_ir);
  k_sink<<<384, 1024, 0, stream>>>(ws_tr, ws_ir, attn_mask, ws_cxx,
                                   ws_sxy, ws_sxx, ws_syy);
  k_final<<<2, 64, 0, stream>>>(ws_mix, ws_sxy, ws_sxx, ws_syy, (float*)d_out);
}

// Round 2
// 501.189 us; speedup vs baseline: 1.8895x; 1.8895x over previous
//
#include <hip/hip_runtime.h>

typedef float  f32x4 __attribute__((ext_vector_type(4)));
typedef short  s16x8 __attribute__((ext_vector_type(8)));

#define EPS_LN2      0.0017328679513998632f   /* eps*ln2, eps = 0.0025 */
#define INV_EPS_LN2  577.0780163555852f       /* 1/(eps*ln2) */
#define LOG2_36      5.169925001442312f

__device__ __forceinline__ short f2bf(float x) {
  unsigned int u; __builtin_memcpy(&u, &x, 4);
  u = (u + 0x7FFFu + ((u >> 16) & 1u)) >> 16;   // RNE
  return (short)u;
}

// ---------------------------------------------------------------------------
// Pack W_rt [768,50] and W_ri [2048,50] into MFMA B-fragment order (bf16),
// N padded 50->64 with zeros. Frag f = (k32*4 + ct)*64 + lane, 8 bf16 each.
// ---------------------------------------------------------------------------
__global__ __launch_bounds__(256) void k_pack(const float* __restrict__ W_rt,
                                              const float* __restrict__ W_ri,
                                              short* __restrict__ frt,
                                              short* __restrict__ fri) {
  int slot = blockIdx.x * 256 + threadIdx.x;   // 22528 total
  const float* W; short* dst; int f;
  if (slot < 6144) { W = W_rt; dst = frt; f = slot; }
  else             { W = W_ri; dst = fri; f = slot - 6144; }
  int k32 = f >> 8, rem = f & 255, ct = rem >> 6, l = rem & 63;
  int col = ct * 16 + (l & 15);
  int k0  = k32 * 32 + (l >> 4) * 8;
  s16x8 p;
#pragma unroll
  for (int c = 0; c < 8; ++c) {
    float v = (col < 50) ? W[(k0 + c) * 50 + col] : 0.f;
    p[c] = f2bf(v);
  }
  *(s16x8*)(dst + (long)f * 8) = p;
}

// ---------------------------------------------------------------------------
// Projection GEMM: out[M][64] = relu(A[M][K] @ W + bias), bf16 MFMA.
// ---------------------------------------------------------------------------
template<int K32>
__global__ __launch_bounds__(256) void k_proj(const float* __restrict__ A,
                                              const short* __restrict__ Bf,
                                              const float* __restrict__ bias,
                                              float* __restrict__ out) {
  int wave = threadIdx.x >> 6, lane = threadIdx.x & 63;
  int tile = blockIdx.x * 4 + wave;
  int row0 = tile * 16;
  int rl = lane & 15, q = lane >> 4;
  const int K = K32 * 32;
  const float* ar = A + (long)(row0 + rl) * K + q * 8;
  f32x4 acc[4];
#pragma unroll
  for (int ct = 0; ct < 4; ++ct) acc[ct] = (f32x4){0.f, 0.f, 0.f, 0.f};
  for (int k32 = 0; k32 < K32; ++k32) {
    f32x4 a0 = *(const f32x4*)(ar + k32 * 32);
    f32x4 a1 = *(const f32x4*)(ar + k32 * 32 + 4);
    s16x8 af;
    af[0]=f2bf(a0[0]); af[1]=f2bf(a0[1]); af[2]=f2bf(a0[2]); af[3]=f2bf(a0[3]);
    af[4]=f2bf(a1[0]); af[5]=f2bf(a1[1]); af[6]=f2bf(a1[2]); af[7]=f2bf(a1[3]);
    const short* bp = Bf + (long)(k32 * 4) * 512 + lane * 8;
#pragma unroll
    for (int ct = 0; ct < 4; ++ct) {
      s16x8 bfr = *(const s16x8*)(bp + ct * 512);
      acc[ct] = __builtin_amdgcn_mfma_f32_16x16x32_bf16(af, bfr, acc[ct], 0, 0, 0);
    }
  }
#pragma unroll
  for (int ct = 0; ct < 4; ++ct) {
    int col = ct * 16 + rl;
    float bv = (col < 50) ? bias[col] : 0.f;
#pragma unroll
    for (int r = 0; r < 4; ++r) {
      int grow = row0 + q * 4 + r;               // D row = quad*4+reg (m89)
      float o = fmaxf(acc[ct][r] + bv, 0.f);
      out[(long)grow * 64 + col] = (col < 50) ? o : 0.f;
    }
  }
}

// ---------------------------------------------------------------------------
// soc = relu(social @ W_stat + b_stat)   [128][100]
// ---------------------------------------------------------------------------
__global__ __launch_bounds__(256) void k_soc(const float* __restrict__ social,
                                             const float* __restrict__ W_stat,
                                             const float* __restrict__ b_stat,
                                             float* __restrict__ soc) {
  int idx = blockIdx.x * 256 + threadIdx.x;
  if (idx < 12800) {
    int r = idx / 100, c = idx - r * 100;
    float a = b_stat[c];
#pragma unroll
    for (int k = 0; k < 10; ++k) a += social[r * 10 + k] * W_stat[k * 100 + c];
    soc[idx] = fmaxf(a, 0.f);
  }
}

// ---------------------------------------------------------------------------
// K-split GEMM for the two big MLP matmuls (no bias, no relu here):
//   pre1 += txt[128,768] @ W_gt[0:768]  and  soc[128,100] @ W_gt[768:868]
//   pre2 += img[128,2048] @ W_gi
// grid = 23 jobs x 4 row-tiles x 4 col-tiles. Block: 32 rows x 64 cols.
// ---------------------------------------------------------------------------
__global__ __launch_bounds__(256) void k_gemm(
    const float* __restrict__ txt, const float* __restrict__ img,
    const float* __restrict__ soc,
    const float* __restrict__ W_gt, const float* __restrict__ W_gi,
    float* __restrict__ pre1, float* __restrict__ pre2) {
  __shared__ float sA[32][128];
  int bid = blockIdx.x;
  int job = bid >> 4, rb = (bid >> 2) & 3, cb = bid & 3;
  const float* A; const float* W; float* dst; int K_A, k0, klen;
  if (job < 6)       { A = txt; K_A = 768;  k0 = job * 128;     klen = 128; W = W_gt;           dst = pre1; }
  else if (job == 6) { A = soc; K_A = 100;  k0 = 0;             klen = 100; W = W_gt + 768*200; dst = pre1; }
  else               { A = img; K_A = 2048; k0 = (job - 7)*128; klen = 128; W = W_gi;           dst = pre2; }
  int t = threadIdx.x, r0 = rb * 32;
  for (int idx = t; idx < 4096; idx += 256) {
    int r = idx >> 7, k = idx & 127;
    sA[r][k] = (k < klen) ? A[(r0 + r) * K_A + k0 + k] : 0.f;
  }
  __syncthreads();
  int c = cb * 64 + (t & 63), rg = t >> 6;
  if (c < 200) {
    float acc[8];
#pragma unroll
    for (int i = 0; i < 8; ++i) acc[i] = 0.f;
    for (int k4 = 0; k4 < klen; k4 += 4) {
      float w0 = W[(k0 + k4    ) * 200 + c];
      float w1 = W[(k0 + k4 + 1) * 200 + c];
      float w2 = W[(k0 + k4 + 2) * 200 + c];
      float w3 = W[(k0 + k4 + 3) * 200 + c];
#pragma unroll
      for (int i = 0; i < 8; ++i) {
        f32x4 a = *(const f32x4*)&sA[rg * 8 + i][k4];
        acc[i] += a[0]*w0 + a[1]*w1 + a[2]*w2 + a[3]*w3;
      }
    }
#pragma unroll
    for (int i = 0; i < 8; ++i)
      atomicAdd(&dst[(r0 + rg * 8 + i) * 200 + c], acc[i]);
  }
}

// ---------------------------------------------------------------------------
// MLP tail: sm=relu(pre1+b_gt)+relu(pre2+b_gi); h=relu(sm@W_m1+b_m1);
// mix = h@W_m2 + b_m2.  One block per batch row.
// ---------------------------------------------------------------------------
__global__ __launch_bounds__(256) void k_mix(
    const float* __restrict__ pre1, const float* __restrict__ pre2,
    const float* __restrict__ b_gt, const float* __restrict__ b_gi,
    const float* __restrict__ W_m1, const float* __restrict__ b_m1,
    const float* __restrict__ W_m2, const float* __restrict__ b_m2,
    float* __restrict__ mix) {
  __shared__ float sm[200];
  __shared__ float sh[100];
  int r = blockIdx.x, t = threadIdx.x;
  if (t < 200)
    sm[t] = fmaxf(pre1[r * 200 + t] + b_gt[t], 0.f) +
            fmaxf(pre2[r * 200 + t] + b_gi[t], 0.f);
  __syncthreads();
  if (t < 100) {
    float a = b_m1[t];
#pragma unroll 4
    for (int k = 0; k < 200; ++k) a += sm[k] * W_m1[k * 100 + t];
    sh[t] = fmaxf(a, 0.f);
  }
  __syncthreads();
  if (t < 2) {
    float a = b_m2[t];
    for (int k = 0; k < 100; ++k) a += sh[k] * W_m2[k * 2 + t];
    mix[r * 2 + t] = a;
  }
}

// ---------------------------------------------------------------------------
// Merged Sinkhorn kernel. role 0: xx (n x n), role 1: xy (n x 36),
// role 2: yy (36 x 36). Log-domain, exp2 units, D = -C/(eps*ln2).
// launch_bounds(1024,4): 128-VGPR cap so Creg[64] stays in registers.
// ---------------------------------------------------------------------------
#define SK_SMEM 50736

__global__ __launch_bounds__(1024, 4) void k_sink(
    const float* __restrict__ tr, const float* __restrict__ ir,
    const int* __restrict__ amask, float* __restrict__ Cxx,
    float* __restrict__ Sxy, float* __restrict__ Sxx, float* __restrict__ Syy) {
  __shared__ __align__(16) char smem[SK_SMEM];
  int role = blockIdx.x >> 7;
  int b    = blockIdx.x & 127;
  int tid  = threadIdx.x;

  if (role == 0) {
    // ====================== XX ======================
    short* Xf    = (short*)smem;                 // 32 KB
    float* norms = (float*)(smem + 32768);       // [256]
    float* sA    = (float*)(smem + 33792);       // [256]
    float* sF    = (float*)(smem + 34816);       // [256]
    float* sG    = (float*)(smem + 35840);       // [256]
    float* sPm   = (float*)(smem + 36864);       // [4][256]
    float* sPs   = (float*)(smem + 40960);       // [4][256]
    int*   nsh   = (int*)  (smem + 45056);
    if (tid < 64) {
      int c = 0;
      for (int i = tid; i < 256; i += 64) c += amask[b * 256 + i];
#pragma unroll
      for (int o = 1; o < 64; o <<= 1) c += __shfl_xor(c, o);
      if (tid == 0) *nsh = c;
    }
    const float* Xg = tr + (long)b * 256 * 64;
    for (int slot = tid; slot < 2048; slot += 1024) {
      int t = slot >> 7, k32 = (slot >> 6) & 1, l = slot & 63;
      int row = t * 16 + (l & 15), k0 = k32 * 32 + (l >> 4) * 8;
      const float* src = Xg + row * 64 + k0;
      f32x4 a0 = *(const f32x4*)src, a1 = *(const f32x4*)(src + 4);
      s16x8 p;
      p[0]=f2bf(a0[0]); p[1]=f2bf(a0[1]); p[2]=f2bf(a0[2]); p[3]=f2bf(a0[3]);
      p[4]=f2bf(a1[0]); p[5]=f2bf(a1[1]); p[6]=f2bf(a1[2]); p[7]=f2bf(a1[3]);
      *(s16x8*)(Xf + slot * 8) = p;
    }
    __syncthreads();
    int n = *nsh;
    // G = X X^T via MFMA. wave wv owns 16-row strip.
    int wv = tid >> 6, lane = tid & 63, q = lane >> 4;
    f32x4 acc[16];
#pragma unroll
    for (int ct = 0; ct < 16; ++ct) acc[ct] = (f32x4){0.f, 0.f, 0.f, 0.f};
    s16x8 afr0 = *(const s16x8*)(Xf + ((wv * 2 + 0) * 64 + lane) * 8);
    s16x8 afr1 = *(const s16x8*)(Xf + ((wv * 2 + 1) * 64 + lane) * 8);
#pragma unroll
    for (int ct = 0; ct < 16; ++ct) {
      s16x8 b0 = *(const s16x8*)(Xf + ((ct * 2 + 0) * 64 + lane) * 8);
      s16x8 b1 = *(const s16x8*)(Xf + ((ct * 2 + 1) * 64 + lane) * 8);
      acc[ct] = __builtin_amdgcn_mfma_f32_16x16x32_bf16(afr0, b0, acc[ct], 0, 0, 0);
      acc[ct] = __builtin_amdgcn_mfma_f32_16x16x32_bf16(afr1, b1, acc[ct], 0, 0, 0);
    }
#pragma unroll
    for (int r = 0; r < 4; ++r) {                 // diag of tile (wv,wv) = ||x||^2
      int m_ = q * 4 + r;
      if ((lane & 15) == m_) norms[wv * 16 + m_] = acc[wv][r];
    }
    __syncthreads();
    float* Cwb = Cxx + (long)b * 65536;           // D = -C/(eps ln2), f32, global
#pragma unroll
    for (int ct = 0; ct < 16; ++ct) {
      int gj = ct * 16 + (lane & 15);
      float nj = norms[gj];
#pragma unroll
      for (int r = 0; r < 4; ++r) {
        int gi = wv * 16 + q * 4 + r;
        Cwb[gi * 256 + gj] = (acc[ct][r] - 0.5f * (norms[gi] + nj)) * INV_EPS_LN2;
      }
    }
    __syncthreads();
    // kk wave-uniform: waves 0-3 -> kk=0, ... so prefix-skipping has no divergence
    int kk = tid >> 8, j = tid & 255, i0 = kk * 64;
    float Creg[64];
#pragma unroll
    for (int t = 0; t < 64; ++t) Creg[t] = Cwb[(i0 + t) * 256 + j];
    float log2n = log2f((float)n);
    if (tid < 256) { sF[tid] = 0.f; sA[tid] = (tid < n) ? -log2n : -1e30f; }
    __syncthreads();
    int iend = n - i0; if (iend > 64) iend = 64;
    for (int h = 0; h < 40; ++h) {
      float m = -1e30f, s = 0.f;
#pragma unroll
      for (int ch = 0; ch < 4; ++ch) {
        if (ch * 16 < iend) {                      // wave-uniform branch
          float x[16];
#pragma unroll
          for (int u = 0; u < 16; ++u) x[u] = sA[i0 + ch * 16 + u] + Creg[ch * 16 + u];
          float mc = x[0];
#pragma unroll
          for (int u = 1; u < 16; ++u) mc = fmaxf(mc, x[u]);
          float mn = fmaxf(m, mc);
          float sc = 0.f;
#pragma unroll
          for (int u = 0; u < 16; ++u) sc += exp2f(x[u] - mn);
          s = s * exp2f(m - mn) + sc;
          m = mn;
        }
      }
      sPm[tid] = m; sPs[tid] = s;
      __syncthreads();
      if (tid < n) {
        float m0 = sPm[tid], m1 = sPm[256 + tid], m2 = sPm[512 + tid], m3 = sPm[768 + tid];
        float m4 = fmaxf(fmaxf(m0, m1), fmaxf(m2, m3));
        float s4 = sPs[tid] * exp2f(m0 - m4) + sPs[256 + tid] * exp2f(m1 - m4)
                 + sPs[512 + tid] * exp2f(m2 - m4) + sPs[768 + tid] * exp2f(m3 - m4);
        float lse = log2f(s4) + m4;
        ((h & 1) ? sF : sG)[tid] = -EPS_LN2 * lse;
        sA[tid] = -log2n - lse;
      }
      __syncthreads();
    }
    if (tid < 64) {
      float a = 0.f;
      for (int i = tid; i < n; i += 64) a += sF[i] + sG[i];
#pragma unroll
      for (int o = 1; o < 64; o <<= 1) a += __shfl_xor(a, o);
      if (tid == 0) Sxx[b] = a / n;
    }
  } else if (role == 1) {
    // ====================== XY ======================
    float* Ys  = (float*)smem;                    // [36][64]
    float* Cs  = (float*)(smem + 9216);           // [256][37]
    float* nx  = (float*)(smem + 47104);          // [256]
    float* ny  = (float*)(smem + 48128);          // [36]
    float* sA  = (float*)(smem + 48288);          // padded alpha [272]
    float* sB  = (float*)(smem + 49376);          // beta [36]
    float* sF  = (float*)(smem + 49536);          // [256]
    float* sG  = (float*)(smem + 50560);          // [36]
    int*   nsh = (int*)  (smem + 50720);
    if (tid < 64) {
      int c = 0;
      for (int i = tid; i < 256; i += 64) c += amask[b * 256 + i];
#pragma unroll
      for (int o = 1; o < 64; o <<= 1) c += __shfl_xor(c, o);
      if (tid == 0) *nsh = c;
    }
    const float* Xg = tr + (long)b * 256 * 64;
    const float* Yg = ir + (long)b * 36 * 64;
    for (int idx = tid; idx < 576; idx += 1024) {
      int row = idx >> 4, q4 = idx & 15;
      *(f32x4*)(Ys + row * 64 + q4 * 4) = *(const f32x4*)(Yg + row * 64 + q4 * 4);
    }
    __syncthreads();
    int n = *nsh;
    if (tid < 256) {
      float a = 0.f;
#pragma unroll
      for (int q4 = 0; q4 < 13; ++q4) {
        f32x4 v = *(const f32x4*)(Xg + tid * 64 + q4 * 4);
        a += v[0]*v[0] + v[1]*v[1] + v[2]*v[2] + v[3]*v[3];
      }
      nx[tid] = a;
    } else if (tid < 292) {
      int jj = tid - 256; float a = 0.f;
#pragma unroll
      for (int q4 = 0; q4 < 13; ++q4) {
        f32x4 v = *(const f32x4*)(Ys + jj * 64 + q4 * 4);
        a += v[0]*v[0] + v[1]*v[1] + v[2]*v[2] + v[3]*v[3];
      }
      ny[jj] = a;
    }
    __syncthreads();
    if (tid < 1008) {
      int ii = tid / 36, jj = tid - ii * 36;
      f32x4 yr[13];
#pragma unroll
      for (int q4 = 0; q4 < 13; ++q4) yr[q4] = *(const f32x4*)(Ys + jj * 64 + q4 * 4);
      float nyj = ny[jj];
      for (int i = ii; i < 256; i += 28) {
        float d = 0.f;
#pragma unroll
        for (int q4 = 0; q4 < 13; ++q4) {
          f32x4 xv = *(const f32x4*)(Xg + i * 64 + q4 * 4);
          d += xv[0]*yr[q4][0] + xv[1]*yr[q4][1] + xv[2]*yr[q4][2] + xv[3]*yr[q4][3];
        }
        Cs[i * 37 + jj] = (d - 0.5f * (nx[i] + nyj)) * INV_EPS_LN2;
      }
    }
    __syncthreads();
    int jg = tid >> 4, kg = tid & 15;             // g-role: column jg, slice kg
    float Cg[16];
    if (jg < 36) {
#pragma unroll
      for (int t = 0; t < 16; ++t) Cg[t] = Cs[(kg * 16 + t) * 37 + jg];
    }
    int fi = tid >> 2, kf = tid & 3;              // f-role: row fi, slice kf
    float Cf[9];
#pragma unroll
    for (int t = 0; t < 9; ++t) {
      int jj2 = kf * 9 + t;
      Cf[t] = (jj2 < 36) ? Cs[fi * 37 + jj2] : 0.f;
    }
    float log2n = log2f((float)n);
    if (tid < 256) { sF[tid] = 0.f; sA[tid + (tid >> 4)] = -log2n; }
    __syncthreads();
    const float* agp = sA + kg * 17;
    int gend = n - kg * 16; if (gend > 16) gend = 16;
    for (int it = 0; it < 20; ++it) {
      float gm = -1e30f, gs = 0.f;
      if (jg < 36) {
#pragma unroll
        for (int t = 0; t < 16; ++t)
          if (t < gend) gm = fmaxf(gm, agp[t] + Cg[t]);
        gm = fmaxf(gm, __shfl_xor(gm, 1)); gm = fmaxf(gm, __shfl_xor(gm, 2));
        gm = fmaxf(gm, __shfl_xor(gm, 4)); gm = fmaxf(gm, __shfl_xor(gm, 8));
#pragma unroll
        for (int t = 0; t < 16; ++t)
          if (t < gend) gs += exp2f(agp[t] + Cg[t] - gm);
        gs += __shfl_xor(gs, 1); gs += __shfl_xor(gs, 2);
        gs += __shfl_xor(gs, 4); gs += __shfl_xor(gs, 8);
      }
      __syncthreads();
      if (jg < 36 && kg == 0) {
        float lse = log2f(gs) + gm;
        sG[jg] = -EPS_LN2 * lse;
        sB[jg] = -LOG2_36 - lse;
      }
      __syncthreads();
      float fm = -1e30f, fs = 0.f;
#pragma unroll
      for (int t = 0; t < 9; ++t) {
        int jj2 = kf * 9 + t;
        if (jj2 < 36) fm = fmaxf(fm, sB[jj2] + Cf[t]);
      }
      fm = fmaxf(fm, __shfl_xor(fm, 1)); fm = fmaxf(fm, __shfl_xor(fm, 2));
#pragma unroll
      for (int t = 0; t < 9; ++t) {
        int jj2 = kf * 9 + t;
        if (jj2 < 36) fs += exp2f(sB[jj2] + Cf[t] - fm);
      }
      fs += __shfl_xor(fs, 1); fs += __shfl_xor(fs, 2);
      __syncthreads();
      if (kf == 0 && fi < n) {
        float lse = log2f(fs) + fm;
        sF[fi] = -EPS_LN2 * lse;
        sA[fi + (fi >> 4)] = -log2n - lse;
      }
      __syncthreads();
    }
    if (tid < 64) {
      float a = 0.f;
      for (int i = tid; i < n; i += 64) a += sF[i];
      float g = (tid < 36) ? sG[tid] : 0.f;
#pragma unroll
      for (int o = 1; o < 64; o <<= 1) { a += __shfl_xor(a, o); g += __shfl_xor(g, o); }
      if (tid == 0) Sxy[b] = a / n + g / 36.f;
    }
  } else {
    // ====================== YY ======================
    float* Ys = (float*)smem;                     // [36][64]
    float* Cs = (float*)(smem + 9216);            // [36][37]
    float* ny = (float*)(smem + 48128);
    float* sA = (float*)(smem + 48288);           // [36]
    float* sF = (float*)(smem + 49536);
    float* sG = (float*)(smem + 50560);
    const float* Yg = ir + (long)b * 36 * 64;
    for (int idx = tid; idx < 576; idx += 1024) {
      int row = idx >> 4, q4 = idx & 15;
      *(f32x4*)(Ys + row * 64 + q4 * 4) = *(const f32x4*)(Yg + row * 64 + q4 * 4);
    }
    __syncthreads();
    if (tid < 36) {
      float a = 0.f;
#pragma unroll
      for (int q4 = 0; q4 < 13; ++q4) {
        f32x4 v = *(const f32x4*)(Ys + tid * 64 + q4 * 4);
        a += v[0]*v[0] + v[1]*v[1] + v[2]*v[2] + v[3]*v[3];
      }
      ny[tid] = a;
    }
    __syncthreads();
    if (tid < 1008) {
      int ii = tid / 36, jj = tid - ii * 36;
      f32x4 yr[13];
#pragma unroll
      for (int q4 = 0; q4 < 13; ++q4) yr[q4] = *(const f32x4*)(Ys + jj * 64 + q4 * 4);
      float nyj = ny[jj];
      for (int i = ii; i < 36; i += 28) {
        float d = 0.f;
#pragma unroll
        for (int q4 = 0; q4 < 13; ++q4) {
          f32x4 xv = *(const f32x4*)(Ys + i * 64 + q4 * 4);
          d += xv[0]*yr[q4][0] + xv[1]*yr[q4][1] + xv[2]*yr[q4][2] + xv[3]*yr[q4][3];
        }
        Cs[i * 37 + jj] = (d - 0.5f * (ny[i] + nyj)) * INV_EPS_LN2;
      }
    }
    __syncthreads();
    int j = tid >> 2, kk = tid & 3;
    float Creg[9];
    if (j < 36) {
#pragma unroll
      for (int t = 0; t < 9; ++t) {
        int i2 = kk * 9 + t;
        Creg[t] = (i2 < 36) ? Cs[i2 * 37 + j] : 0.f;
      }
    }
    if (tid < 36) { sF[tid] = 0.f; sA[tid] = -LOG2_36; }
    __syncthreads();
    for (int h = 0; h < 40; ++h) {
      float m = -1e30f, s = 0.f;
      if (j < 36) {
#pragma unroll
        for (int t = 0; t < 9; ++t) {
          int i2 = kk * 9 + t;
          if (i2 < 36) m = fmaxf(m, sA[i2] + Creg[t]);
        }
        m = fmaxf(m, __shfl_xor(m, 1)); m = fmaxf(m, __shfl_xor(m, 2));
#pragma unroll
        for (int t = 0; t < 9; ++t) {
          int i2 = kk * 9 + t;
          if (i2 < 36) s += exp2f(sA[i2] + Creg[t] - m);
        }
        s += __shfl_xor(s, 1); s += __shfl_xor(s, 2);
      }
      __syncthreads();
      if (j < 36 && kk == 0) {
        float lse = log2f(s) + m;
        ((h & 1) ? sF : sG)[j] = -EPS_LN2 * lse;
        sA[j] = -LOG2_36 - lse;
      }
      __syncthreads();
    }
    if (tid < 64) {
      float a = (tid < 36) ? sF[tid] + sG[tid] : 0.f;
#pragma unroll
      for (int o = 1; o < 64; o <<= 1) a += __shfl_xor(a, o);
      if (tid == 0) Syy[b] = a / 36.f;
    }
  }
}

// ---------------------------------------------------------------------------
// Final combine: w_dis -> w_pred, max with mix_pred, 2-way softmax.
// ---------------------------------------------------------------------------
__global__ void k_final(const float* __restrict__ mix, const float* __restrict__ sxy,
                        const float* __restrict__ sxx, const float* __restrict__ syy,
                        float* __restrict__ out) {
  int b = blockIdx.x * 64 + threadIdx.x;
  if (b < 128) {
    float w  = sxy[b] - 0.5f * (sxx[b] + syy[b]);
    float x0 = fmaxf(mix[b * 2 + 0], 1.0f - 0.01f * w);
    float x1 = fmaxf(mix[b * 2 + 1], 0.01f * w);
    float mx = fmaxf(x0, x1);
    float e0 = expf(x0 - mx), e1 = expf(x1 - mx);
    float inv = 1.f / (e0 + e1);
    out[b * 2 + 0] = e0 * inv;
    out[b * 2 + 1] = e1 * inv;
  }
}

// ---------------------------------------------------------------------------
extern "C" void kernel_launch(void* const* d_in, const int* in_sizes, int n_in,
                              void* d_out, int out_size, void* d_ws, size_t ws_size,
                              hipStream_t stream) {
  const float* txt_global = (const float*)d_in[0];
  const float* txt_region = (const float*)d_in[1];
  const float* img_global = (const float*)d_in[2];
  const float* img_region = (const float*)d_in[3];
  const float* social     = (const float*)d_in[4];
  const int*   attn_mask  = (const int*)  d_in[5];
  const float* W_stat = (const float*)d_in[6];  const float* b_stat = (const float*)d_in[7];
  const float* W_gt   = (const float*)d_in[8];  const float* b_gt   = (const float*)d_in[9];
  const float* W_gi   = (const float*)d_in[10]; const float* b_gi   = (const float*)d_in[11];
  const float* W_rt   = (const float*)d_in[12]; const float* b_rt   = (const float*)d_in[13];
  const float* W_ri   = (const float*)d_in[14]; const float* b_ri   = (const float*)d_in[15];
  const float* W_m1   = (const float*)d_in[16]; const float* b_m1   = (const float*)d_in[17];
  const float* W_m2   = (const float*)d_in[18]; const float* b_m2   = (const float*)d_in[19];

  float* ws = (float*)d_ws;
  float* ws_mix = ws;                    // 256
  float* ws_sxy = ws + 256;              // 128
  float* ws_sxx = ws + 384;              // 128
  float* ws_syy = ws + 512;              // 128
  short* ws_frt = (short*)(ws + 1024);   // 24576 floats
  short* ws_fri = (short*)(ws + 25600);  // 65536 floats -> ends 91136
  float* ws_soc  = ws + 91136;           // [128][100] -> ends 103936
  float* ws_pre1 = ws + 103936;          // [128][200] -> ends 129536 (< 131072)
  float* ws_tr  = ws + 131072;           // [32768][64]
  float* ws_ir  = ws + 2228224;          // [4608][64]
  float* ws_cxx = ws + 2523136;          // [128][256][256]
  float* ws_pre2 = ws_cxx;               // reuse cxx head: consumed by k_mix BEFORE k_sink writes

  hipMemsetAsync(ws_pre1, 0, 25600 * sizeof(float), stream);
  hipMemsetAsync(ws_pre2, 0, 25600 * sizeof(float), stream);
  k_pack<<<88, 256, 0, stream>>>(W_rt, W_ri, ws_frt, ws_fri);
  k_soc<<<50, 256, 0, stream>>>(social, W_stat, b_stat, ws_soc);
  k_gemm<<<368, 256, 0, stream>>>(txt_global, img_global, ws_soc,
                                  W_gt, W_gi, ws_pre1, ws_pre2);
  k_mix<<<128, 256, 0, stream>>>(ws_pre1, ws_pre2, b_gt, b_gi,
                                 W_m1, b_m1, W_m2, b_m2, ws_mix);
  k_proj<24><<<512, 256, 0, stream>>>(txt_region, ws_frt, b_rt, ws_tr);
  k_proj<64><<<72, 256, 0, stream>>>(img_region, ws_fri, b_ri, ws_ir);
  k_sink<<<384, 1024, 0, stream>>>(ws_tr, ws_ir, attn_mask, ws_cxx,
                                   ws_sxy, ws_sxx, ws_syy);
  k_final<<<2, 64, 0, stream>>>(ws_mix, ws_sxy, ws_sxx, ws_syy, (float*)d_out);
}

// Round 3
// 347.629 us; speedup vs baseline: 2.7242x; 1.4417x over previous
//
#include <hip/hip_runtime.h>

typedef float  f32x4 __attribute__((ext_vector_type(4)));
typedef short  s16x8 __attribute__((ext_vector_type(8)));

#define EPS_LN2      0.0017328679513998632f   /* eps*ln2, eps = 0.0025 */
#define INV_EPS_LN2  577.0780163555852f       /* 1/(eps*ln2) */
#define LOG2_36      5.169925001442312f

__device__ __forceinline__ short f2bf(float x) {
  unsigned int u; __builtin_memcpy(&u, &x, 4);
  u = (u + 0x7FFFu + ((u >> 16) & 1u)) >> 16;   // RNE
  return (short)u;
}

// ---------------------------------------------------------------------------
// Pack W_rt [768,50] and W_ri [2048,50] into MFMA B-fragment order (bf16),
// N padded 50->64 with zeros. Also zeroes pre1/pre2 accumulators.
// ---------------------------------------------------------------------------
__global__ __launch_bounds__(256) void k_pack(const float* __restrict__ W_rt,
                                              const float* __restrict__ W_ri,
                                              short* __restrict__ frt,
                                              short* __restrict__ fri,
                                              float* __restrict__ pre1,
                                              float* __restrict__ pre2) {
  int slot = blockIdx.x * 256 + threadIdx.x;   // 22528 total
  for (int z = slot; z < 25600; z += 22528) { pre1[z] = 0.f; pre2[z] = 0.f; }
  const float* W; short* dst; int f;
  if (slot < 6144) { W = W_rt; dst = frt; f = slot; }
  else             { W = W_ri; dst = fri; f = slot - 6144; }
  int k32 = f >> 8, rem = f & 255, ct = rem >> 6, l = rem & 63;
  int col = ct * 16 + (l & 15);
  int k0  = k32 * 32 + (l >> 4) * 8;
  s16x8 p;
#pragma unroll
  for (int c = 0; c < 8; ++c) {
    float v = (col < 50) ? W[(k0 + c) * 50 + col] : 0.f;
    p[c] = f2bf(v);
  }
  *(s16x8*)(dst + (long)f * 8) = p;
}

// ---------------------------------------------------------------------------
// K-split GEMM for the two big MLP matmuls (accumulated via atomics):
//   pre1 += txt[128,768] @ W_gt[0:768]  and  soc @ W_gt[768:868] (job 6
//   computes soc = relu(social@W_stat+b_stat) inline)
//   pre2 += img[128,2048] @ W_gi
// ---------------------------------------------------------------------------
__global__ __launch_bounds__(256) void k_gemm(
    const float* __restrict__ txt, const float* __restrict__ img,
    const float* __restrict__ social,
    const float* __restrict__ W_stat, const float* __restrict__ b_stat,
    const float* __restrict__ W_gt, const float* __restrict__ W_gi,
    float* __restrict__ pre1, float* __restrict__ pre2) {
  __shared__ float sA[32][128];
  int bid = blockIdx.x;
  int job = bid >> 4, rb = (bid >> 2) & 3, cb = bid & 3;
  int t = threadIdx.x, r0 = rb * 32;
  const float* W; float* dst; int k0, klen;
  if (job < 6)       { k0 = job * 128;     klen = 128; W = W_gt;             dst = pre1; }
  else if (job == 6) { k0 = 0;             klen = 100; W = W_gt + 768 * 200; dst = pre1; }
  else               { k0 = (job - 7)*128; klen = 128; W = W_gi;             dst = pre2; }
  if (job == 6) {
    // compute soc tile inline: sA[r][k] = relu(b_stat[k] + social[r]·W_stat[:,k])
    for (int idx = t; idx < 4096; idx += 256) {
      int r = idx >> 7, k = idx & 127;
      float v = 0.f;
      if (k < 100) {
        v = b_stat[k];
#pragma unroll
        for (int u = 0; u < 10; ++u) v += social[(r0 + r) * 10 + u] * W_stat[u * 100 + k];
        v = fmaxf(v, 0.f);
      }
      sA[r][k] = v;
    }
  } else {
    const float* A = (job < 6) ? txt : img;
    int K_A = (job < 6) ? 768 : 2048;
    for (int idx = t; idx < 4096; idx += 256) {
      int r = idx >> 7, k = idx & 127;
      sA[r][k] = A[(r0 + r) * K_A + k0 + k];
    }
  }
  __syncthreads();
  int c = cb * 64 + (t & 63), rg = t >> 6;
  if (c < 200) {
    float acc[8];
#pragma unroll
    for (int i = 0; i < 8; ++i) acc[i] = 0.f;
    for (int k4 = 0; k4 < klen; k4 += 4) {
      float w0 = W[(k0 + k4    ) * 200 + c];
      float w1 = W[(k0 + k4 + 1) * 200 + c];
      float w2 = W[(k0 + k4 + 2) * 200 + c];
      float w3 = W[(k0 + k4 + 3) * 200 + c];
#pragma unroll
      for (int i = 0; i < 8; ++i) {
        f32x4 a = *(const f32x4*)&sA[rg * 8 + i][k4];
        acc[i] += a[0]*w0 + a[1]*w1 + a[2]*w2 + a[3]*w3;
      }
    }
#pragma unroll
    for (int i = 0; i < 8; ++i)
      atomicAdd(&dst[(r0 + rg * 8 + i) * 200 + c], acc[i]);
  }
}

// ---------------------------------------------------------------------------
// Projection GEMM body: out[M][64] = relu(A[M][K] @ W + bias), bf16 MFMA.
// ---------------------------------------------------------------------------
template<int K32>
__device__ __forceinline__ void proj_body(const float* __restrict__ A,
                                          const short* __restrict__ Bf,
                                          const float* __restrict__ bias,
                                          float* __restrict__ out, int bid) {
  int wave = threadIdx.x >> 6, lane = threadIdx.x & 63;
  int tile = bid * 4 + wave;
  int row0 = tile * 16;
  int rl = lane & 15, q = lane >> 4;
  const int K = K32 * 32;
  const float* ar = A + (long)(row0 + rl) * K + q * 8;
  f32x4 acc[4];
#pragma unroll
  for (int ct = 0; ct < 4; ++ct) acc[ct] = (f32x4){0.f, 0.f, 0.f, 0.f};
  for (int k32 = 0; k32 < K32; ++k32) {
    f32x4 a0 = *(const f32x4*)(ar + k32 * 32);
    f32x4 a1 = *(const f32x4*)(ar + k32 * 32 + 4);
    s16x8 af;
    af[0]=f2bf(a0[0]); af[1]=f2bf(a0[1]); af[2]=f2bf(a0[2]); af[3]=f2bf(a0[3]);
    af[4]=f2bf(a1[0]); af[5]=f2bf(a1[1]); af[6]=f2bf(a1[2]); af[7]=f2bf(a1[3]);
    const short* bp = Bf + (long)(k32 * 4) * 512 + lane * 8;
#pragma unroll
    for (int ct = 0; ct < 4; ++ct) {
      s16x8 bfr = *(const s16x8*)(bp + ct * 512);
      acc[ct] = __builtin_amdgcn_mfma_f32_16x16x32_bf16(af, bfr, acc[ct], 0, 0, 0);
    }
  }
#pragma unroll
  for (int ct = 0; ct < 4; ++ct) {
    int col = ct * 16 + rl;
    float bv = (col < 50) ? bias[col] : 0.f;
#pragma unroll
    for (int r = 0; r < 4; ++r) {
      int grow = row0 + q * 4 + r;               // D row = quad*4+reg (m89)
      float o = fmaxf(acc[ct][r] + bv, 0.f);
      out[(long)grow * 64 + col] = (col < 50) ? o : 0.f;
    }
  }
}

// MLP tail body: one block per batch row.
__device__ __forceinline__ void mix_body(
    int r, const float* __restrict__ pre1, const float* __restrict__ pre2,
    const float* __restrict__ b_gt, const float* __restrict__ b_gi,
    const float* __restrict__ W_m1, const float* __restrict__ b_m1,
    const float* __restrict__ W_m2, const float* __restrict__ b_m2,
    float* __restrict__ mix) {
  __shared__ float sm[200];
  __shared__ float sh[100];
  int t = threadIdx.x;
  if (t < 200)
    sm[t] = fmaxf(pre1[r * 200 + t] + b_gt[t], 0.f) +
            fmaxf(pre2[r * 200 + t] + b_gi[t], 0.f);
  __syncthreads();
  if (t < 100) {
    float a = b_m1[t];
#pragma unroll 4
    for (int k = 0; k < 200; ++k) a += sm[k] * W_m1[k * 100 + t];
    sh[t] = fmaxf(a, 0.f);
  }
  __syncthreads();
  if (t < 2) {
    float a = b_m2[t];
    for (int k = 0; k < 100; ++k) a += sh[k] * W_m2[k * 2 + t];
    mix[r * 2 + t] = a;
  }
}

// Merged: blocks [0,512) txt proj, [512,584) img proj, [584,712) mix rows.
__global__ __launch_bounds__(256) void k_pm(
    const float* __restrict__ txt_region, const short* __restrict__ frt,
    const float* __restrict__ b_rt, float* __restrict__ tr,
    const float* __restrict__ img_region, const short* __restrict__ fri,
    const float* __restrict__ b_ri, float* __restrict__ ir,
    const float* __restrict__ pre1, const float* __restrict__ pre2,
    const float* __restrict__ b_gt, const float* __restrict__ b_gi,
    const float* __restrict__ W_m1, const float* __restrict__ b_m1,
    const float* __restrict__ W_m2, const float* __restrict__ b_m2,
    float* __restrict__ mix) {
  int bid = blockIdx.x;
  if (bid < 512)      proj_body<24>(txt_region, frt, b_rt, tr, bid);
  else if (bid < 584) proj_body<64>(img_region, fri, b_ri, ir, bid - 512);
  else mix_body(bid - 584, pre1, pre2, b_gt, b_gi, W_m1, b_m1, W_m2, b_m2, mix);
}

// ---------------------------------------------------------------------------
// Merged Sinkhorn kernel, MAX-PLUS (lse ~= max at eps=0.0025; error per step
// ~EPS_LN2*log2(#near-ties) ~ 1e-4 in f-units, tolerance is 2.8 in w-units).
// role 0: xx (n x n), role 1: xy (n x 36), role 2: yy (36 x 36).
// waves_per_eu(4,4): pin 128-VGPR budget so Creg[64] is register-resident
// (R2's VGPR=60 meant Creg spilled -> ~1.3GB scratch traffic = entire 210us).
// ---------------------------------------------------------------------------
#define SK_SMEM 50736

__global__ __launch_bounds__(1024)
__attribute__((amdgpu_waves_per_eu(4, 4)))
void k_sink(
    const float* __restrict__ tr, const float* __restrict__ ir,
    const int* __restrict__ amask, float* __restrict__ Cxx,
    float* __restrict__ Sxy, float* __restrict__ Sxx, float* __restrict__ Syy) {
  __shared__ __align__(16) char smem[SK_SMEM];
  int role = blockIdx.x >> 7;
  int b    = blockIdx.x & 127;
  int tid  = threadIdx.x;

  if (role == 0) {
    // ====================== XX ======================
    short* Xf    = (short*)smem;                 // 32 KB
    float* norms = (float*)(smem + 32768);       // [256]
    float* sA    = (float*)(smem + 33792);       // [256]
    float* sF    = (float*)(smem + 34816);       // [256]
    float* sG    = (float*)(smem + 35840);       // [256]
    float* sPm   = (float*)(smem + 36864);       // [4][256]
    int*   nsh   = (int*)  (smem + 40960);
    if (tid < 64) {
      int c = 0;
      for (int i = tid; i < 256; i += 64) c += amask[b * 256 + i];
#pragma unroll
      for (int o = 1; o < 64; o <<= 1) c += __shfl_xor(c, o);
      if (tid == 0) *nsh = c;
    }
    const float* Xg = tr + (long)b * 256 * 64;
    for (int slot = tid; slot < 2048; slot += 1024) {
      int t = slot >> 7, k32 = (slot >> 6) & 1, l = slot & 63;
      int row = t * 16 + (l & 15), k0 = k32 * 32 + (l >> 4) * 8;
      const float* src = Xg + row * 64 + k0;
      f32x4 a0 = *(const f32x4*)src, a1 = *(const f32x4*)(src + 4);
      s16x8 p;
      p[0]=f2bf(a0[0]); p[1]=f2bf(a0[1]); p[2]=f2bf(a0[2]); p[3]=f2bf(a0[3]);
      p[4]=f2bf(a1[0]); p[5]=f2bf(a1[1]); p[6]=f2bf(a1[2]); p[7]=f2bf(a1[3]);
      *(s16x8*)(Xf + slot * 8) = p;
    }
    __syncthreads();
    int n = *nsh;
    // G = X X^T via MFMA. wave wv owns 16-row strip.
    int wv = tid >> 6, lane = tid & 63, q = lane >> 4;
    f32x4 acc[16];
#pragma unroll
    for (int ct = 0; ct < 16; ++ct) acc[ct] = (f32x4){0.f, 0.f, 0.f, 0.f};
    s16x8 afr0 = *(const s16x8*)(Xf + ((wv * 2 + 0) * 64 + lane) * 8);
    s16x8 afr1 = *(const s16x8*)(Xf + ((wv * 2 + 1) * 64 + lane) * 8);
#pragma unroll
    for (int ct = 0; ct < 16; ++ct) {
      s16x8 b0 = *(const s16x8*)(Xf + ((ct * 2 + 0) * 64 + lane) * 8);
      s16x8 b1 = *(const s16x8*)(Xf + ((ct * 2 + 1) * 64 + lane) * 8);
      acc[ct] = __builtin_amdgcn_mfma_f32_16x16x32_bf16(afr0, b0, acc[ct], 0, 0, 0);
      acc[ct] = __builtin_amdgcn_mfma_f32_16x16x32_bf16(afr1, b1, acc[ct], 0, 0, 0);
    }
#pragma unroll
    for (int r = 0; r < 4; ++r) {                 // diag of tile (wv,wv) = ||x||^2
      int m_ = q * 4 + r;
      if ((lane & 15) == m_) norms[wv * 16 + m_] = acc[wv][r];
    }
    __syncthreads();
    float* Cwb = Cxx + (long)b * 65536;           // D = -C/(eps ln2), f32, global
    if (wv * 16 < n) {                            // skip row-tiles entirely >= n
#pragma unroll
      for (int ct = 0; ct < 16; ++ct) {
        int gj = ct * 16 + (lane & 15);
        float nj = norms[gj];
#pragma unroll
        for (int r = 0; r < 4; ++r) {
          int gi = wv * 16 + q * 4 + r;
          Cwb[gi * 256 + gj] = (acc[ct][r] - 0.5f * (norms[gi] + nj)) * INV_EPS_LN2;
        }
      }
    }
    __syncthreads();
    // kk wave-uniform so prefix-skipping has no divergence
    int kk = tid >> 8, j = tid & 255, i0 = kk * 64;
    int iend = n - i0; if (iend > 64) iend = 64;
    float Creg[64];
    if (j < n) {
#pragma unroll
      for (int ch = 0; ch < 4; ++ch) {
        if (ch * 16 < iend) {
#pragma unroll
          for (int u = 0; u < 16; ++u)
            Creg[ch * 16 + u] = Cwb[(i0 + ch * 16 + u) * 256 + j];
        }
      }
    }
    float log2n = log2f((float)n);
    if (tid < 256) { sF[tid] = 0.f; sA[tid] = (tid < n) ? -log2n : -1e30f; }
    __syncthreads();
    const float* ap = sA + i0;
    for (int h = 0; h < 40; ++h) {
      float m = -1e30f;
      if (j < n) {
#pragma unroll
        for (int ch = 0; ch < 4; ++ch) {
          if (ch * 16 < iend) {                   // wave-uniform chunk skip
            f32x4 a0 = *(const f32x4*)(ap + ch * 16);
            f32x4 a1 = *(const f32x4*)(ap + ch * 16 + 4);
            f32x4 a2 = *(const f32x4*)(ap + ch * 16 + 8);
            f32x4 a3 = *(const f32x4*)(ap + ch * 16 + 12);
            float t0 = fmaxf(a0[0] + Creg[ch*16+0],  a0[1] + Creg[ch*16+1]);
            float t1 = fmaxf(a0[2] + Creg[ch*16+2],  a0[3] + Creg[ch*16+3]);
            float t2 = fmaxf(a1[0] + Creg[ch*16+4],  a1[1] + Creg[ch*16+5]);
            float t3 = fmaxf(a1[2] + Creg[ch*16+6],  a1[3] + Creg[ch*16+7]);
            float t4 = fmaxf(a2[0] + Creg[ch*16+8],  a2[1] + Creg[ch*16+9]);
            float t5 = fmaxf(a2[2] + Creg[ch*16+10], a2[3] + Creg[ch*16+11]);
            float t6 = fmaxf(a3[0] + Creg[ch*16+12], a3[1] + Creg[ch*16+13]);
            float t7 = fmaxf(a3[2] + Creg[ch*16+14], a3[3] + Creg[ch*16+15]);
            float u0 = fmaxf(fmaxf(t0, t1), fmaxf(t2, t3));
            float u1 = fmaxf(fmaxf(t4, t5), fmaxf(t6, t7));
            m = fmaxf(m, fmaxf(u0, u1));
          }
        }
      }
      sPm[kk * 256 + j] = m;
      __syncthreads();
      if (tid < 256) {
        float m4 = fmaxf(fmaxf(sPm[tid], sPm[256 + tid]),
                         fmaxf(sPm[512 + tid], sPm[768 + tid]));
        if (tid < n) {
          ((h & 1) ? sF : sG)[tid] = -EPS_LN2 * m4;
          sA[tid] = -log2n - m4;
        }
      }
      __syncthreads();
    }
    if (tid < 64) {
      float a = 0.f;
      for (int i = tid; i < n; i += 64) a += sF[i] + sG[i];
#pragma unroll
      for (int o = 1; o < 64; o <<= 1) a += __shfl_xor(a, o);
      if (tid == 0) Sxx[b] = a / n;
    }
  } else if (role == 1) {
    // ====================== XY ======================
    float* Ys  = (float*)smem;                    // [36][64]
    float* Cs  = (float*)(smem + 9216);           // [256][37]
    float* nx  = (float*)(smem + 47104);          // [256]
    float* ny  = (float*)(smem + 48128);          // [36]
    float* sA  = (float*)(smem + 48288);          // padded alpha [272]
    float* sB  = (float*)(smem + 49376);          // beta [36]
    float* sF  = (float*)(smem + 49536);          // [256]
    float* sG  = (float*)(smem + 50560);          // [36]
    int*   nsh = (int*)  (smem + 50720);
    if (tid < 64) {
      int c = 0;
      for (int i = tid; i < 256; i += 64) c += amask[b * 256 + i];
#pragma unroll
      for (int o = 1; o < 64; o <<= 1) c += __shfl_xor(c, o);
      if (tid == 0) *nsh = c;
    }
    const float* Xg = tr + (long)b * 256 * 64;
    const float* Yg = ir + (long)b * 36 * 64;
    for (int idx = tid; idx < 576; idx += 1024) {
      int row = idx >> 4, q4 = idx & 15;
      *(f32x4*)(Ys + row * 64 + q4 * 4) = *(const f32x4*)(Yg + row * 64 + q4 * 4);
    }
    __syncthreads();
    int n = *nsh;
    if (tid < 256) {
      float a = 0.f;
#pragma unroll
      for (int q4 = 0; q4 < 13; ++q4) {
        f32x4 v = *(const f32x4*)(Xg + tid * 64 + q4 * 4);
        a += v[0]*v[0] + v[1]*v[1] + v[2]*v[2] + v[3]*v[3];
      }
      nx[tid] = a;
    } else if (tid < 292) {
      int jj = tid - 256; float a = 0.f;
#pragma unroll
      for (int q4 = 0; q4 < 13; ++q4) {
        f32x4 v = *(const f32x4*)(Ys + jj * 64 + q4 * 4);
        a += v[0]*v[0] + v[1]*v[1] + v[2]*v[2] + v[3]*v[3];
      }
      ny[jj] = a;
    }
    __syncthreads();
    if (tid < 1008) {
      int ii = tid / 36, jj = tid - ii * 36;
      f32x4 yr[13];
#pragma unroll
      for (int q4 = 0; q4 < 13; ++q4) yr[q4] = *(const f32x4*)(Ys + jj * 64 + q4 * 4);
      float nyj = ny[jj];
      for (int i = ii; i < 256; i += 28) {
        float d = 0.f;
#pragma unroll
        for (int q4 = 0; q4 < 13; ++q4) {
          f32x4 xv = *(const f32x4*)(Xg + i * 64 + q4 * 4);
          d += xv[0]*yr[q4][0] + xv[1]*yr[q4][1] + xv[2]*yr[q4][2] + xv[3]*yr[q4][3];
        }
        Cs[i * 37 + jj] = (d - 0.5f * (nx[i] + nyj)) * INV_EPS_LN2;
      }
    }
    __syncthreads();
    int jg = tid >> 4, kg = tid & 15;             // g-role: column jg, slice kg
    float Cg[16];
    if (jg < 36) {
#pragma unroll
      for (int t = 0; t < 16; ++t) Cg[t] = Cs[(kg * 16 + t) * 37 + jg];
    }
    int fi = tid >> 2, kf = tid & 3;              // f-role: row fi, slice kf
    float Cf[9];
#pragma unroll
    for (int t = 0; t < 9; ++t) {
      int jj2 = kf * 9 + t;
      Cf[t] = (jj2 < 36) ? Cs[fi * 37 + jj2] : 0.f;
    }
    float log2n = log2f((float)n);
    if (tid < 256) { sF[tid] = 0.f; sA[tid + (tid >> 4)] = -log2n; }
    __syncthreads();
    const float* agp = sA + kg * 17;
    int gend = n - kg * 16; if (gend > 16) gend = 16;
    for (int it = 0; it < 20; ++it) {
      float gm = -1e30f;
      if (jg < 36) {
#pragma unroll
        for (int t = 0; t < 16; ++t)
          if (t < gend) gm = fmaxf(gm, agp[t] + Cg[t]);
        gm = fmaxf(gm, __shfl_xor(gm, 1)); gm = fmaxf(gm, __shfl_xor(gm, 2));
        gm = fmaxf(gm, __shfl_xor(gm, 4)); gm = fmaxf(gm, __shfl_xor(gm, 8));
      }
      __syncthreads();
      if (jg < 36 && kg == 0) {
        sG[jg] = -EPS_LN2 * gm;
        sB[jg] = -LOG2_36 - gm;
      }
      __syncthreads();
      float fm = -1e30f;
#pragma unroll
      for (int t = 0; t < 9; ++t) {
        int jj2 = kf * 9 + t;
        if (jj2 < 36) fm = fmaxf(fm, sB[jj2] + Cf[t]);
      }
      fm = fmaxf(fm, __shfl_xor(fm, 1)); fm = fmaxf(fm, __shfl_xor(fm, 2));
      __syncthreads();
      if (kf == 0 && fi < n) {
        sF[fi] = -EPS_LN2 * fm;
        sA[fi + (fi >> 4)] = -log2n - fm;
      }
      __syncthreads();
    }
    if (tid < 64) {
      float a = 0.f;
      for (int i = tid; i < n; i += 64) a += sF[i];
      float g = (tid < 36) ? sG[tid] : 0.f;
#pragma unroll
      for (int o = 1; o < 64; o <<= 1) { a += __shfl_xor(a, o); g += __shfl_xor(g, o); }
      if (tid == 0) Sxy[b] = a / n + g / 36.f;
    }
  } else {
    // ====================== YY ======================
    float* Ys = (float*)smem;                     // [36][64]
    float* Cs = (float*)(smem + 9216);            // [36][37]
    float* ny = (float*)(smem + 48128);
    float* sA = (float*)(smem + 48288);           // [36]
    float* sF = (float*)(smem + 49536);
    float* sG = (float*)(smem + 50560);
    const float* Yg = ir + (long)b * 36 * 64;
    for (int idx = tid; idx < 576; idx += 1024) {
      int row = idx >> 4, q4 = idx & 15;
      *(f32x4*)(Ys + row * 64 + q4 * 4) = *(const f32x4*)(Yg + row * 64 + q4 * 4);
    }
    __syncthreads();
    if (tid < 36) {
      float a = 0.f;
#pragma unroll
      for (int q4 = 0; q4 < 13; ++q4) {
        f32x4 v = *(const f32x4*)(Ys + tid * 64 + q4 * 4);
        a += v[0]*v[0] + v[1]*v[1] + v[2]*v[2] + v[3]*v[3];
      }
      ny[tid] = a;
    }
    __syncthreads();
    if (tid < 1008) {
      int ii = tid / 36, jj = tid - ii * 36;
      f32x4 yr[13];
#pragma unroll
      for (int q4 = 0; q4 < 13; ++q4) yr[q4] = *(const f32x4*)(Ys + jj * 64 + q4 * 4);
      float nyj = ny[jj];
      for (int i = ii; i < 36; i += 28) {
        float d = 0.f;
#pragma unroll
        for (int q4 = 0; q4 < 13; ++q4) {
          f32x4 xv = *(const f32x4*)(Ys + i * 64 + q4 * 4);
          d += xv[0]*yr[q4][0] + xv[1]*yr[q4][1] + xv[2]*yr[q4][2] + xv[3]*yr[q4][3];
        }
        Cs[i * 37 + jj] = (d - 0.5f * (ny[i] + nyj)) * INV_EPS_LN2;
      }
    }
    __syncthreads();
    int j = tid >> 2, kk = tid & 3;
    float Creg[9];
    if (j < 36) {
#pragma unroll
      for (int t = 0; t < 9; ++t) {
        int i2 = kk * 9 + t;
        Creg[t] = (i2 < 36) ? Cs[i2 * 37 + j] : 0.f;
      }
    }
    if (tid < 36) { sF[tid] = 0.f; sA[tid] = -LOG2_36; }
    __syncthreads();
    for (int h = 0; h < 40; ++h) {
      float m = -1e30f;
      if (j < 36) {
#pragma unroll
        for (int t = 0; t < 9; ++t) {
          int i2 = kk * 9 + t;
          if (i2 < 36) m = fmaxf(m, sA[i2] + Creg[t]);
        }
        m = fmaxf(m, __shfl_xor(m, 1)); m = fmaxf(m, __shfl_xor(m, 2));
      }
      __syncthreads();
      if (j < 36 && kk == 0) {
        ((h & 1) ? sF : sG)[j] = -EPS_LN2 * m;
        sA[j] = -LOG2_36 - m;
      }
      __syncthreads();
    }
    if (tid < 64) {
      float a = (tid < 36) ? sF[tid] + sG[tid] : 0.f;
#pragma unroll
      for (int o = 1; o < 64; o <<= 1) a += __shfl_xor(a, o);
      if (tid == 0) Syy[b] = a / 36.f;
    }
  }
}

// ---------------------------------------------------------------------------
// Final combine: w_dis -> w_pred, max with mix_pred, 2-way softmax.
// ---------------------------------------------------------------------------
__global__ void k_final(const float* __restrict__ mix, const float* __restrict__ sxy,
                        const float* __restrict__ sxx, const float* __restrict__ syy,
                        float* __restrict__ out) {
  int b = blockIdx.x * 64 + threadIdx.x;
  if (b < 128) {
    float w  = sxy[b] - 0.5f * (sxx[b] + syy[b]);
    float x0 = fmaxf(mix[b * 2 + 0], 1.0f - 0.01f * w);
    float x1 = fmaxf(mix[b * 2 + 1], 0.01f * w);
    float mx = fmaxf(x0, x1);
    float e0 = expf(x0 - mx), e1 = expf(x1 - mx);
    float inv = 1.f / (e0 + e1);
    out[b * 2 + 0] = e0 * inv;
    out[b * 2 + 1] = e1 * inv;
  }
}

// ---------------------------------------------------------------------------
extern "C" void kernel_launch(void* const* d_in, const int* in_sizes, int n_in,
                              void* d_out, int out_size, void* d_ws, size_t ws_size,
                              hipStream_t stream) {
  const float* txt_global = (const float*)d_in[0];
  const float* txt_region = (const float*)d_in[1];
  const float* img_global = (const float*)d_in[2];
  const float* img_region = (const float*)d_in[3];
  const float* social     = (const float*)d_in[4];
  const int*   attn_mask  = (const int*)  d_in[5];
  const float* W_stat = (const float*)d_in[6];  const float* b_stat = (const float*)d_in[7];
  const float* W_gt   = (const float*)d_in[8];  const float* b_gt   = (const float*)d_in[9];
  const float* W_gi   = (const float*)d_in[10]; const float* b_gi   = (const float*)d_in[11];
  const float* W_rt   = (const float*)d_in[12]; const float* b_rt   = (const float*)d_in[13];
  const float* W_ri   = (const float*)d_in[14]; const float* b_ri   = (const float*)d_in[15];
  const float* W_m1   = (const float*)d_in[16]; const float* b_m1   = (const float*)d_in[17];
  const float* W_m2   = (const float*)d_in[18]; const float* b_m2   = (const float*)d_in[19];

  float* ws = (float*)d_ws;
  float* ws_mix = ws;                    // 256
  float* ws_sxy = ws + 256;              // 128
  float* ws_sxx = ws + 384;              // 128
  float* ws_syy = ws + 512;              // 128
  short* ws_frt = (short*)(ws + 1024);   // 12288 shorts
  short* ws_fri = (short*)(ws + 25600);  // 131072 shorts -> ends 91136
  float* ws_pre1 = ws + 103936;          // [128][200] -> ends 129536
  float* ws_tr  = ws + 131072;           // [32768][64]
  float* ws_ir  = ws + 2228224;          // [4608][64]
  float* ws_cxx = ws + 2523136;          // [128][256][256]
  float* ws_pre2 = ws_cxx;               // reuse cxx head: consumed before k_sink writes

  k_pack<<<88, 256, 0, stream>>>(W_rt, W_ri, ws_frt, ws_fri, ws_pre1, ws_pre2);
  k_gemm<<<368, 256, 0, stream>>>(txt_global, img_global, social,
                                  W_stat, b_stat, W_gt, W_gi, ws_pre1, ws_pre2);
  k_pm<<<712, 256, 0, stream>>>(txt_region, ws_frt, b_rt, ws_tr,
                                img_region, ws_fri, b_ri, ws_ir,
                                ws_pre1, ws_pre2, b_gt, b_gi,
                                W_m1, b_m1, W_m2, b_m2, ws_mix);
  k_sink<<<384, 1024, 0, stream>>>(ws_tr, ws_ir, attn_mask, ws_cxx,
                                   ws_sxy, ws_sxx, ws_syy);
  k_final<<<2, 64, 0, stream>>>(ws_mix, ws_sxy, ws_sxx, ws_syy, (float*)d_out);
}

// Round 4
// 340.834 us; speedup vs baseline: 2.7785x; 1.0199x over previous
//
#include <hip/hip_runtime.h>

typedef float  f32x4 __attribute__((ext_vector_type(4)));
typedef short  s16x8 __attribute__((ext_vector_type(8)));

#define EPS_LN2      0.0017328679513998632f   /* eps*ln2, eps = 0.0025 */
#define INV_EPS_LN2  577.0780163555852f       /* 1/(eps*ln2) */
#define LOG2_36      5.169925001442312f

__device__ __forceinline__ short f2bf(float x) {
  unsigned int u; __builtin_memcpy(&u, &x, 4);
  u = (u + 0x7FFFu + ((u >> 16) & 1u)) >> 16;   // RNE
  return (short)u;
}

// ---------------------------------------------------------------------------
// k_prep: blocks [0,88) pack W_rt/W_ri into MFMA B-frag order (bf16);
// blocks [88,456) K-split GEMM writing per-job slices pre[23][128][200]
// (no atomics, no zero-init needed).
// ---------------------------------------------------------------------------
__global__ __launch_bounds__(256) void k_prep(
    const float* __restrict__ W_rt, const float* __restrict__ W_ri,
    short* __restrict__ frt, short* __restrict__ fri,
    const float* __restrict__ txt, const float* __restrict__ img,
    const float* __restrict__ social,
    const float* __restrict__ W_stat, const float* __restrict__ b_stat,
    const float* __restrict__ W_gt, const float* __restrict__ W_gi,
    float* __restrict__ pre) {
  __shared__ float sA[32][128];
  int bid = blockIdx.x;
  if (bid < 88) {
    // ---- pack ----
    int slot = bid * 256 + threadIdx.x;   // 22528 total
    const float* W; short* dst; int f;
    if (slot < 6144) { W = W_rt; dst = frt; f = slot; }
    else             { W = W_ri; dst = fri; f = slot - 6144; }
    int k32 = f >> 8, rem = f & 255, ct = rem >> 6, l = rem & 63;
    int col = ct * 16 + (l & 15);
    int k0  = k32 * 32 + (l >> 4) * 8;
    s16x8 p;
#pragma unroll
    for (int c = 0; c < 8; ++c) {
      float v = (col < 50) ? W[(k0 + c) * 50 + col] : 0.f;
      p[c] = f2bf(v);
    }
    *(s16x8*)(dst + (long)f * 8) = p;
    return;
  }
  // ---- gemm: job slice pre[job] = A_chunk @ W_chunk ----
  int gb = bid - 88;
  int job = gb >> 4, rb = (gb >> 2) & 3, cb = gb & 3;
  int t = threadIdx.x, r0 = rb * 32;
  const float* W; int k0, klen;
  if (job < 6)       { k0 = job * 128;       klen = 128; W = W_gt; }
  else if (job == 6) { k0 = 0;               klen = 100; W = W_gt + 768 * 200; }
  else               { k0 = (job - 7) * 128; klen = 128; W = W_gi; }
  if (job == 6) {
    for (int idx = t; idx < 4096; idx += 256) {
      int r = idx >> 7, k = idx & 127;
      float v = 0.f;
      if (k < 100) {
        v = b_stat[k];
#pragma unroll
        for (int u = 0; u < 10; ++u) v += social[(r0 + r) * 10 + u] * W_stat[u * 100 + k];
        v = fmaxf(v, 0.f);
      }
      sA[r][k] = v;
    }
  } else {
    const float* A = (job < 6) ? txt : img;
    int K_A = (job < 6) ? 768 : 2048;
    for (int idx = t; idx < 4096; idx += 256) {
      int r = idx >> 7, k = idx & 127;
      sA[r][k] = A[(r0 + r) * K_A + k0 + k];
    }
  }
  __syncthreads();
  int c = cb * 64 + (t & 63), rg = t >> 6;
  if (c < 200) {
    float acc[8];
#pragma unroll
    for (int i = 0; i < 8; ++i) acc[i] = 0.f;
    for (int k4 = 0; k4 < klen; k4 += 4) {
      float w0 = W[(k0 + k4    ) * 200 + c];
      float w1 = W[(k0 + k4 + 1) * 200 + c];
      float w2 = W[(k0 + k4 + 2) * 200 + c];
      float w3 = W[(k0 + k4 + 3) * 200 + c];
#pragma unroll
      for (int i = 0; i < 8; ++i) {
        f32x4 a = *(const f32x4*)&sA[rg * 8 + i][k4];
        acc[i] += a[0]*w0 + a[1]*w1 + a[2]*w2 + a[3]*w3;
      }
    }
    float* dst = pre + (long)job * 25600;
#pragma unroll
    for (int i = 0; i < 8; ++i)
      dst[(r0 + rg * 8 + i) * 200 + c] = acc[i];
  }
}

// ---------------------------------------------------------------------------
// Projection GEMM body with LDS B-frag windows (8 k32 = 32KB, double-buffered
// via register staging) + depth-1 A register prefetch.
// out[M][64] = relu(A[M][K] @ W + bias). One block = 64 rows (4 waves x 16).
// ---------------------------------------------------------------------------
template<int K32>
__device__ __forceinline__ void proj_body(const float* __restrict__ A,
                                          const short* __restrict__ Bf,
                                          const float* __restrict__ bias,
                                          float* __restrict__ out, int bid,
                                          char* smem) {
  short* sB = (short*)smem;                     // [2][16384] shorts = 64KB
  const int NWIN = K32 / 8;
  int wave = threadIdx.x >> 6, lane = threadIdx.x & 63;
  int rl = lane & 15, q = lane >> 4;
  int row0 = bid * 64 + wave * 16;
  const int K = K32 * 32;
  const float* ar = A + (long)(row0 + rl) * K + q * 8;
  int soff = wave * 4096 + lane * 8;            // this wave's chunk base (shorts)

  // preload window 0 into regs, store to buf 0
  f32x4 stage[8];
#pragma unroll
  for (int c = 0; c < 8; ++c)
    stage[c] = *(const f32x4*)(Bf + (long)soff + c * 512);
#pragma unroll
  for (int c = 0; c < 8; ++c)
    *(f32x4*)(sB + soff + c * 512) = stage[c];
  // preload A for k32=0
  f32x4 a0 = *(const f32x4*)(ar);
  f32x4 a1 = *(const f32x4*)(ar + 4);
  f32x4 acc[4];
#pragma unroll
  for (int ct = 0; ct < 4; ++ct) acc[ct] = (f32x4){0.f, 0.f, 0.f, 0.f};
  __syncthreads();

  for (int w = 0; w < NWIN; ++w) {
    if (w + 1 < NWIN) {                         // issue next-window loads early
      const short* src = Bf + (long)(w + 1) * 16384 + soff;
#pragma unroll
      for (int c = 0; c < 8; ++c) stage[c] = *(const f32x4*)(src + c * 512);
    }
    const short* bbuf = sB + (w & 1) * 16384;
#pragma unroll
    for (int kk8 = 0; kk8 < 8; ++kk8) {
      int k32 = w * 8 + kk8;
      f32x4 na0, na1;
      if (k32 + 1 < K32) {                      // depth-1 A prefetch
        na0 = *(const f32x4*)(ar + (k32 + 1) * 32);
        na1 = *(const f32x4*)(ar + (k32 + 1) * 32 + 4);
      }
      s16x8 af;
      af[0]=f2bf(a0[0]); af[1]=f2bf(a0[1]); af[2]=f2bf(a0[2]); af[3]=f2bf(a0[3]);
      af[4]=f2bf(a1[0]); af[5]=f2bf(a1[1]); af[6]=f2bf(a1[2]); af[7]=f2bf(a1[3]);
      const short* bp = bbuf + kk8 * 2048 + lane * 8;
#pragma unroll
      for (int ct = 0; ct < 4; ++ct) {
        s16x8 bfr = *(const s16x8*)(bp + ct * 512);
        acc[ct] = __builtin_amdgcn_mfma_f32_16x16x32_bf16(af, bfr, acc[ct], 0, 0, 0);
      }
      a0 = na0; a1 = na1;
    }
    if (w + 1 < NWIN) {
      __syncthreads();                          // all readers done with other buf
      short* nbuf = sB + ((w + 1) & 1) * 16384;
#pragma unroll
      for (int c = 0; c < 8; ++c) *(f32x4*)(nbuf + soff + c * 512) = stage[c];
      __syncthreads();
    }
  }
#pragma unroll
  for (int ct = 0; ct < 4; ++ct) {
    int col = ct * 16 + rl;
    float bv = (col < 50) ? bias[col] : 0.f;
#pragma unroll
    for (int r = 0; r < 4; ++r) {
      int grow = row0 + q * 4 + r;               // D row = quad*4+reg (m89)
      float o = fmaxf(acc[ct][r] + bv, 0.f);
      out[(long)grow * 64 + col] = (col < 50) ? o : 0.f;
    }
  }
}

// MLP tail body: one block per batch row; sums the 23 per-job GEMM slices.
__device__ __forceinline__ void mix_body(
    int r, const float* __restrict__ pre,
    const float* __restrict__ b_gt, const float* __restrict__ b_gi,
    const float* __restrict__ W_m1, const float* __restrict__ b_m1,
    const float* __restrict__ W_m2, const float* __restrict__ b_m2,
    float* __restrict__ mix, char* smem) {
  float* sm = (float*)smem;         // [200]
  float* sh = (float*)(smem + 800); // [100]
  int t = threadIdx.x;
  if (t < 200) {
    float s1 = b_gt[t], s2 = b_gi[t];
#pragma unroll
    for (int j = 0; j < 7; ++j)  s1 += pre[(long)j * 25600 + r * 200 + t];
#pragma unroll
    for (int j = 7; j < 23; ++j) s2 += pre[(long)j * 25600 + r * 200 + t];
    sm[t] = fmaxf(s1, 0.f) + fmaxf(s2, 0.f);
  }
  __syncthreads();
  if (t < 100) {
    float a = b_m1[t];
#pragma unroll 4
    for (int k = 0; k < 200; ++k) a += sm[k] * W_m1[k * 100 + t];
    sh[t] = fmaxf(a, 0.f);
  }
  __syncthreads();
  if (t < 2) {
    float a = b_m2[t];
    for (int k = 0; k < 100; ++k) a += sh[k] * W_m2[k * 2 + t];
    mix[r * 2 + t] = a;
  }
}

// Merged: blocks [0,128) mix rows (first: no serial tail), [128,640) txt proj,
// [640,712) img proj.
__global__ __launch_bounds__(256)
__attribute__((amdgpu_waves_per_eu(4, 4)))
void k_pm(
    const float* __restrict__ txt_region, const short* __restrict__ frt,
    const float* __restrict__ b_rt, float* __restrict__ tr,
    const float* __restrict__ img_region, const short* __restrict__ fri,
    const float* __restrict__ b_ri, float* __restrict__ ir,
    const float* __restrict__ pre,
    const float* __restrict__ b_gt, const float* __restrict__ b_gi,
    const float* __restrict__ W_m1, const float* __restrict__ b_m1,
    const float* __restrict__ W_m2, const float* __restrict__ b_m2,
    float* __restrict__ mix) {
  __shared__ __align__(16) char smem[65536];
  int bid = blockIdx.x;
  if (bid < 128)      mix_body(bid, pre, b_gt, b_gi, W_m1, b_m1, W_m2, b_m2, mix, smem);
  else if (bid < 640) proj_body<24>(txt_region, frt, b_rt, tr, bid - 128, smem);
  else                proj_body<64>(img_region, fri, b_ri, ir, bid - 640, smem);
}

// ---------------------------------------------------------------------------
// Merged Sinkhorn kernel, MAX-PLUS. role 0: xx (n x n), role 1: xy (n x 36),
// role 2: yy (36 x 36). waves_per_eu(4,4): 128-VGPR budget, Creg in regs.
// ---------------------------------------------------------------------------
#define SK_SMEM 50736

__global__ __launch_bounds__(1024)
__attribute__((amdgpu_waves_per_eu(4, 4)))
void k_sink(
    const float* __restrict__ tr, const float* __restrict__ ir,
    const int* __restrict__ amask, float* __restrict__ Cxx,
    float* __restrict__ Sxy, float* __restrict__ Sxx, float* __restrict__ Syy) {
  __shared__ __align__(16) char smem[SK_SMEM];
  int role = blockIdx.x >> 7;
  int b    = blockIdx.x & 127;
  int tid  = threadIdx.x;

  if (role == 0) {
    // ====================== XX ======================
    short* Xf    = (short*)smem;                 // 32 KB
    float* norms = (float*)(smem + 32768);       // [256]
    float* sA    = (float*)(smem + 33792);       // [256]
    float* sF    = (float*)(smem + 34816);       // [256]
    float* sG    = (float*)(smem + 35840);       // [256]
    float* sPm   = (float*)(smem + 36864);       // [4][256]
    int*   nsh   = (int*)  (smem + 40960);
    if (tid < 64) {
      int c = 0;
      for (int i = tid; i < 256; i += 64) c += amask[b * 256 + i];
#pragma unroll
      for (int o = 1; o < 64; o <<= 1) c += __shfl_xor(c, o);
      if (tid == 0) *nsh = c;
    }
    const float* Xg = tr + (long)b * 256 * 64;
    for (int slot = tid; slot < 2048; slot += 1024) {
      int t = slot >> 7, k32 = (slot >> 6) & 1, l = slot & 63;
      int row = t * 16 + (l & 15), k0 = k32 * 32 + (l >> 4) * 8;
      const float* src = Xg + row * 64 + k0;
      f32x4 a0 = *(const f32x4*)src, a1 = *(const f32x4*)(src + 4);
      s16x8 p;
      p[0]=f2bf(a0[0]); p[1]=f2bf(a0[1]); p[2]=f2bf(a0[2]); p[3]=f2bf(a0[3]);
      p[4]=f2bf(a1[0]); p[5]=f2bf(a1[1]); p[6]=f2bf(a1[2]); p[7]=f2bf(a1[3]);
      *(s16x8*)(Xf + slot * 8) = p;
    }
    __syncthreads();
    int n = *nsh;
    // G = X X^T via MFMA. wave wv owns 16-row strip.
    int wv = tid >> 6, lane = tid & 63, q = lane >> 4;
    f32x4 acc[16];
#pragma unroll
    for (int ct = 0; ct < 16; ++ct) acc[ct] = (f32x4){0.f, 0.f, 0.f, 0.f};
    s16x8 afr0 = *(const s16x8*)(Xf + ((wv * 2 + 0) * 64 + lane) * 8);
    s16x8 afr1 = *(const s16x8*)(Xf + ((wv * 2 + 1) * 64 + lane) * 8);
#pragma unroll
    for (int ct = 0; ct < 16; ++ct) {
      s16x8 b0 = *(const s16x8*)(Xf + ((ct * 2 + 0) * 64 + lane) * 8);
      s16x8 b1 = *(const s16x8*)(Xf + ((ct * 2 + 1) * 64 + lane) * 8);
      acc[ct] = __builtin_amdgcn_mfma_f32_16x16x32_bf16(afr0, b0, acc[ct], 0, 0, 0);
      acc[ct] = __builtin_amdgcn_mfma_f32_16x16x32_bf16(afr1, b1, acc[ct], 0, 0, 0);
    }
#pragma unroll
    for (int r = 0; r < 4; ++r) {                 // diag of tile (wv,wv) = ||x||^2
      int m_ = q * 4 + r;
      if ((lane & 15) == m_) norms[wv * 16 + m_] = acc[wv][r];
    }
    __syncthreads();
    float* Cwb = Cxx + (long)b * 65536;           // D = -C/(eps ln2), f32, global
    if (wv * 16 < n) {                            // skip row-tiles entirely >= n
#pragma unroll
      for (int ct = 0; ct < 16; ++ct) {
        int gj = ct * 16 + (lane & 15);
        float nj = norms[gj];
#pragma unroll
        for (int r = 0; r < 4; ++r) {
          int gi = wv * 16 + q * 4 + r;
          Cwb[gi * 256 + gj] = (acc[ct][r] - 0.5f * (norms[gi] + nj)) * INV_EPS_LN2;
        }
      }
    }
    __syncthreads();
    // kk wave-uniform so prefix-skipping has no divergence
    int kk = tid >> 8, j = tid & 255, i0 = kk * 64;
    int iend = n - i0; if (iend > 64) iend = 64;
    float Creg[64];
    if (j < n) {
#pragma unroll
      for (int ch = 0; ch < 4; ++ch) {
        if (ch * 16 < iend) {
#pragma unroll
          for (int u = 0; u < 16; ++u)
            Creg[ch * 16 + u] = Cwb[(i0 + ch * 16 + u) * 256 + j];
        }
      }
    }
    float log2n = log2f((float)n);
    if (tid < 256) { sF[tid] = 0.f; sA[tid] = (tid < n) ? -log2n : -1e30f; }
    __syncthreads();
    const float* ap = sA + i0;
    for (int h = 0; h < 40; ++h) {
      float m = -1e30f;
      if (j < n) {
#pragma unroll
        for (int ch = 0; ch < 4; ++ch) {
          if (ch * 16 < iend) {                   // wave-uniform chunk skip
            const float* app = ap + ch * 16;
            f32x4 A0 = *(const f32x4*)(app);
            f32x4 A1 = *(const f32x4*)(app + 4);
            f32x4 A2 = *(const f32x4*)(app + 8);
            f32x4 A3 = *(const f32x4*)(app + 12);
            float x0 = A0[0]+Creg[ch*16+0],  x1 = A0[1]+Creg[ch*16+1];
            float x2 = A0[2]+Creg[ch*16+2],  x3 = A0[3]+Creg[ch*16+3];
            float x4 = A1[0]+Creg[ch*16+4],  x5 = A1[1]+Creg[ch*16+5];
            float x6 = A1[2]+Creg[ch*16+6],  x7 = A1[3]+Creg[ch*16+7];
            float x8 = A2[0]+Creg[ch*16+8],  x9 = A2[1]+Creg[ch*16+9];
            float xa = A2[2]+Creg[ch*16+10], xb = A2[3]+Creg[ch*16+11];
            float xc = A3[0]+Creg[ch*16+12], xd = A3[1]+Creg[ch*16+13];
            float xe = A3[2]+Creg[ch*16+14], xf = A3[3]+Creg[ch*16+15];
            // max3 trees (v_max3_f32)
            float y0 = fmaxf(fmaxf(x0, x1), x2);
            float y1 = fmaxf(fmaxf(x3, x4), x5);
            float y2 = fmaxf(fmaxf(x6, x7), x8);
            float y3 = fmaxf(fmaxf(x9, xa), xb);
            float y4 = fmaxf(fmaxf(xc, xd), xe);
            float z0 = fmaxf(fmaxf(y0, y1), y2);
            float z1 = fmaxf(fmaxf(y3, y4), xf);
            m = fmaxf(fmaxf(m, z0), z1);
          }
        }
      }
      sPm[kk * 256 + j] = m;
      __syncthreads();
      if (tid < 256) {
        float m4 = fmaxf(fmaxf(sPm[tid], sPm[256 + tid]),
                         fmaxf(sPm[512 + tid], sPm[768 + tid]));
        if (tid < n) {
          ((h & 1) ? sF : sG)[tid] = -EPS_LN2 * m4;
          sA[tid] = -log2n - m4;
        }
      }
      __syncthreads();
    }
    if (tid < 64) {
      float a = 0.f;
      for (int i = tid; i < n; i += 64) a += sF[i] + sG[i];
#pragma unroll
      for (int o = 1; o < 64; o <<= 1) a += __shfl_xor(a, o);
      if (tid == 0) Sxx[b] = a / n;
    }
  } else if (role == 1) {
    // ====================== XY ======================
    float* Ys  = (float*)smem;                    // [36][64]
    float* Cs  = (float*)(smem + 9216);           // [256][37]
    float* nx  = (float*)(smem + 47104);          // [256]
    float* ny  = (float*)(smem + 48128);          // [36]
    float* sA  = (float*)(smem + 48288);          // padded alpha [272]
    float* sB  = (float*)(smem + 49376);          // beta [36]
    float* sF  = (float*)(smem + 49536);          // [256]
    float* sG  = (float*)(smem + 50560);          // [36]
    int*   nsh = (int*)  (smem + 50720);
    if (tid < 64) {
      int c = 0;
      for (int i = tid; i < 256; i += 64) c += amask[b * 256 + i];
#pragma unroll
      for (int o = 1; o < 64; o <<= 1) c += __shfl_xor(c, o);
      if (tid == 0) *nsh = c;
    }
    const float* Xg = tr + (long)b * 256 * 64;
    const float* Yg = ir + (long)b * 36 * 64;
    for (int idx = tid; idx < 576; idx += 1024) {
      int row = idx >> 4, q4 = idx & 15;
      *(f32x4*)(Ys + row * 64 + q4 * 4) = *(const f32x4*)(Yg + row * 64 + q4 * 4);
    }
    __syncthreads();
    int n = *nsh;
    if (tid < 256) {
      float a = 0.f;
#pragma unroll
      for (int q4 = 0; q4 < 13; ++q4) {
        f32x4 v = *(const f32x4*)(Xg + tid * 64 + q4 * 4);
        a += v[0]*v[0] + v[1]*v[1] + v[2]*v[2] + v[3]*v[3];
      }
      nx[tid] = a;
    } else if (tid < 292) {
      int jj = tid - 256; float a = 0.f;
#pragma unroll
      for (int q4 = 0; q4 < 13; ++q4) {
        f32x4 v = *(const f32x4*)(Ys + jj * 64 + q4 * 4);
        a += v[0]*v[0] + v[1]*v[1] + v[2]*v[2] + v[3]*v[3];
      }
      ny[jj] = a;
    }
    __syncthreads();
    if (tid < 1008) {
      int ii = tid / 36, jj = tid - ii * 36;
      f32x4 yr[13];
#pragma unroll
      for (int q4 = 0; q4 < 13; ++q4) yr[q4] = *(const f32x4*)(Ys + jj * 64 + q4 * 4);
      float nyj = ny[jj];
      for (int i = ii; i < 256; i += 28) {
        float d = 0.f;
#pragma unroll
        for (int q4 = 0; q4 < 13; ++q4) {
          f32x4 xv = *(const f32x4*)(Xg + i * 64 + q4 * 4);
          d += xv[0]*yr[q4][0] + xv[1]*yr[q4][1] + xv[2]*yr[q4][2] + xv[3]*yr[q4][3];
        }
        Cs[i * 37 + jj] = (d - 0.5f * (nx[i] + nyj)) * INV_EPS_LN2;
      }
    }
    __syncthreads();
    int jg = tid >> 4, kg = tid & 15;             // g-role: column jg, slice kg
    float Cg[16];
    if (jg < 36) {
#pragma unroll
      for (int t = 0; t < 16; ++t) Cg[t] = Cs[(kg * 16 + t) * 37 + jg];
    }
    int fi = tid >> 2, kf = tid & 3;              // f-role: row fi, slice kf
    float Cf[9];
#pragma unroll
    for (int t = 0; t < 9; ++t) {
      int jj2 = kf * 9 + t;
      Cf[t] = (jj2 < 36) ? Cs[fi * 37 + jj2] : 0.f;
    }
    float log2n = log2f((float)n);
    if (tid < 256) { sF[tid] = 0.f; sA[tid + (tid >> 4)] = -log2n; }
    __syncthreads();
    const float* agp = sA + kg * 17;
    int gend = n - kg * 16; if (gend > 16) gend = 16;
    for (int it = 0; it < 20; ++it) {
      float gm = -1e30f;
      if (jg < 36) {
#pragma unroll
        for (int t = 0; t < 16; ++t)
          if (t < gend) gm = fmaxf(gm, agp[t] + Cg[t]);
        gm = fmaxf(gm, __shfl_xor(gm, 1)); gm = fmaxf(gm, __shfl_xor(gm, 2));
        gm = fmaxf(gm, __shfl_xor(gm, 4)); gm = fmaxf(gm, __shfl_xor(gm, 8));
      }
      __syncthreads();
      if (jg < 36 && kg == 0) {
        sG[jg] = -EPS_LN2 * gm;
        sB[jg] = -LOG2_36 - gm;
      }
      __syncthreads();
      float fm = -1e30f;
#pragma unroll
      for (int t = 0; t < 9; ++t) {
        int jj2 = kf * 9 + t;
        if (jj2 < 36) fm = fmaxf(fm, sB[jj2] + Cf[t]);
      }
      fm = fmaxf(fm, __shfl_xor(fm, 1)); fm = fmaxf(fm, __shfl_xor(fm, 2));
      __syncthreads();
      if (kf == 0 && fi < n) {
        sF[fi] = -EPS_LN2 * fm;
        sA[fi + (fi >> 4)] = -log2n - fm;
      }
      __syncthreads();
    }
    if (tid < 64) {
      float a = 0.f;
      for (int i = tid; i < n; i += 64) a += sF[i];
      float g = (tid < 36) ? sG[tid] : 0.f;
#pragma unroll
      for (int o = 1; o < 64; o <<= 1) { a += __shfl_xor(a, o); g += __shfl_xor(g, o); }
      if (tid == 0) Sxy[b] = a / n + g / 36.f;
    }
  } else {
    // ====================== YY ======================
    float* Ys = (float*)smem;                     // [36][64]
    float* Cs = (float*)(smem + 9216);            // [36][37]
    float* ny = (float*)(smem + 48128);
    float* sA = (float*)(smem + 48288);           // [36]
    float* sF = (float*)(smem + 49536);
    float* sG = (float*)(smem + 50560);
    const float* Yg = ir + (long)b * 36 * 64;
    for (int idx = tid; idx < 576; idx += 1024) {
      int row = idx >> 4, q4 = idx & 15;
      *(f32x4*)(Ys + row * 64 + q4 * 4) = *(const f32x4*)(Yg + row * 64 + q4 * 4);
    }
    __syncthreads();
    if (tid < 36) {
      float a = 0.f;
#pragma unroll
      for (int q4 = 0; q4 < 13; ++q4) {
        f32x4 v = *(const f32x4*)(Ys + tid * 64 + q4 * 4);
        a += v[0]*v[0] + v[1]*v[1] + v[2]*v[2] + v[3]*v[3];
      }
      ny[tid] = a;
    }
    __syncthreads();
    if (tid < 1008) {
      int ii = tid / 36, jj = tid - ii * 36;
      f32x4 yr[13];
#pragma unroll
      for (int q4 = 0; q4 < 13; ++q4) yr[q4] = *(const f32x4*)(Ys + jj * 64 + q4 * 4);
      float nyj = ny[jj];
      for (int i = ii; i < 36; i += 28) {
        float d = 0.f;
#pragma unroll
        for (int q4 = 0; q4 < 13; ++q4) {
          f32x4 xv = *(const f32x4*)(Ys + i * 64 + q4 * 4);
          d += xv[0]*yr[q4][0] + xv[1]*yr[q4][1] + xv[2]*yr[q4][2] + xv[3]*yr[q4][3];
        }
        Cs[i * 37 + jj] = (d - 0.5f * (ny[i] + nyj)) * INV_EPS_LN2;
      }
    }
    __syncthreads();
    int j = tid >> 2, kk = tid & 3;
    float Creg[9];
    if (j < 36) {
#pragma unroll
      for (int t = 0; t < 9; ++t) {
        int i2 = kk * 9 + t;
        Creg[t] = (i2 < 36) ? Cs[i2 * 37 + j] : 0.f;
      }
    }
    if (tid < 36) { sF[tid] = 0.f; sA[tid] = -LOG2_36; }
    __syncthreads();
    for (int h = 0; h < 40; ++h) {
      float m = -1e30f;
      if (j < 36) {
#pragma unroll
        for (int t = 0; t < 9; ++t) {
          int i2 = kk * 9 + t;
          if (i2 < 36) m = fmaxf(m, sA[i2] + Creg[t]);
        }
        m = fmaxf(m, __shfl_xor(m, 1)); m = fmaxf(m, __shfl_xor(m, 2));
      }
      __syncthreads();
      if (j < 36 && kk == 0) {
        ((h & 1) ? sF : sG)[j] = -EPS_LN2 * m;
        sA[j] = -LOG2_36 - m;
      }
      __syncthreads();
    }
    if (tid < 64) {
      float a = (tid < 36) ? sF[tid] + sG[tid] : 0.f;
#pragma unroll
      for (int o = 1; o < 64; o <<= 1) a += __shfl_xor(a, o);
      if (tid == 0) Syy[b] = a / 36.f;
    }
  }
}

// ---------------------------------------------------------------------------
// Final combine: w_dis -> w_pred, max with mix_pred, 2-way softmax.
// ---------------------------------------------------------------------------
__global__ void k_final(const float* __restrict__ mix, const float* __restrict__ sxy,
                        const float* __restrict__ sxx, const float* __restrict__ syy,
                        float* __restrict__ out) {
  int b = blockIdx.x * 64 + threadIdx.x;
  if (b < 128) {
    float w  = sxy[b] - 0.5f * (sxx[b] + syy[b]);
    float x0 = fmaxf(mix[b * 2 + 0], 1.0f - 0.01f * w);
    float x1 = fmaxf(mix[b * 2 + 1], 0.01f * w);
    float mx = fmaxf(x0, x1);
    float e0 = expf(x0 - mx), e1 = expf(x1 - mx);
    float inv = 1.f / (e0 + e1);
    out[b * 2 + 0] = e0 * inv;
    out[b * 2 + 1] = e1 * inv;
  }
}

// ---------------------------------------------------------------------------
extern "C" void kernel_launch(void* const* d_in, const int* in_sizes, int n_in,
                              void* d_out, int out_size, void* d_ws, size_t ws_size,
                              hipStream_t stream) {
  const float* txt_global = (const float*)d_in[0];
  const float* txt_region = (const float*)d_in[1];
  const float* img_global = (const float*)d_in[2];
  const float* img_region = (const float*)d_in[3];
  const float* social     = (const float*)d_in[4];
  const int*   attn_mask  = (const int*)  d_in[5];
  const float* W_stat = (const float*)d_in[6];  const float* b_stat = (const float*)d_in[7];
  const float* W_gt   = (const float*)d_in[8];  const float* b_gt   = (const float*)d_in[9];
  const float* W_gi   = (const float*)d_in[10]; const float* b_gi   = (const float*)d_in[11];
  const float* W_rt   = (const float*)d_in[12]; const float* b_rt   = (const float*)d_in[13];
  const float* W_ri   = (const float*)d_in[14]; const float* b_ri   = (const float*)d_in[15];
  const float* W_m1   = (const float*)d_in[16]; const float* b_m1   = (const float*)d_in[17];
  const float* W_m2   = (const float*)d_in[18]; const float* b_m2   = (const float*)d_in[19];

  float* ws = (float*)d_ws;
  float* ws_mix = ws;                    // 256
  float* ws_sxy = ws + 256;              // 128
  float* ws_sxx = ws + 384;              // 128
  float* ws_syy = ws + 512;              // 128
  short* ws_frt = (short*)(ws + 1024);   // 49152 shorts -> ends float 25600
  short* ws_fri = (short*)(ws + 25600);  // 131072 shorts -> ends float 91136
  float* ws_tr  = ws + 131072;           // [32768][64]
  float* ws_ir  = ws + 2228224;          // [4608][64]
  float* ws_cxx = ws + 2523136;          // [128][256][256]
  float* ws_pre = ws_cxx;                // [23][128][200]; consumed by k_pm
                                         // before k_sink overwrites with Cxx

  k_prep<<<456, 256, 0, stream>>>(W_rt, W_ri, ws_frt, ws_fri,
                                  txt_global, img_global, social,
                                  W_stat, b_stat, W_gt, W_gi, ws_pre);
  k_pm<<<712, 256, 0, stream>>>(txt_region, ws_frt, b_rt, ws_tr,
                                img_region, ws_fri, b_ri, ws_ir,
                                ws_pre, b_gt, b_gi,
                                W_m1, b_m1, W_m2, b_m2, ws_mix);
  k_sink<<<384, 1024, 0, stream>>>(ws_tr, ws_ir, attn_mask, ws_cxx,
                                   ws_sxy, ws_sxx, ws_syy);
  k_final<<<2, 64, 0, stream>>>(ws_mix, ws_sxy, ws_sxx, ws_syy, (float*)d_out);
}